// Round 2
// baseline (14155.721 us; speedup 1.0000x reference)
//
#include <hip/hip_runtime.h>
#include <hip/hip_bf16.h>
#include <math.h>

#define NHEAD 4
#define DH 128
#define HID 512
#define NLAY 2
#define NP 30000
#define NA 10000
#define INDIM 768
#define EC 150000
#define EW 80000
#define EB 80000

typedef __hip_bfloat16 bf16;

__device__ __forceinline__ float ldf(const float* p){ return *p; }
__device__ __forceinline__ float ldf(const bf16* p){ return __bfloat162float(*p); }
__device__ __forceinline__ void stf(float* p, float v){ *p = v; }
__device__ __forceinline__ void stf(bf16* p, float v){ *p = __float2bfloat16(v); }

// load 8 consecutive elements starting at element index i8*8 (row must be 16B aligned)
__device__ __forceinline__ void load8(const float* __restrict__ p, int i8, float* o){
  const float4* q = (const float4*)p;
  float4 a = q[i8*2], b = q[i8*2+1];
  o[0]=a.x;o[1]=a.y;o[2]=a.z;o[3]=a.w;o[4]=b.x;o[5]=b.y;o[6]=b.z;o[7]=b.w;
}
__device__ __forceinline__ void load8(const bf16* __restrict__ p, int i8, float* o){
  uint4 r = ((const uint4*)p)[i8];
  o[0]=__uint_as_float(r.x<<16); o[1]=__uint_as_float(r.x&0xffff0000u);
  o[2]=__uint_as_float(r.y<<16); o[3]=__uint_as_float(r.y&0xffff0000u);
  o[4]=__uint_as_float(r.z<<16); o[5]=__uint_as_float(r.z&0xffff0000u);
  o[6]=__uint_as_float(r.w<<16); o[7]=__uint_as_float(r.w&0xffff0000u);
}

// ---------------------------------------------------------------------------
// Tiled GEMM: C[M,N] = A[M,K] @ B[K,N] (+bias) (+relu). B always fp32.
// blockIdx.z batches via element offsets zsA/zsB/zsC. N%64==0, K%16==0.
// ---------------------------------------------------------------------------
template<typename TA, typename TC>
__global__ __launch_bounds__(256)
void gemm_k(const TA* __restrict__ A, int lda, long long zsA,
            const float* __restrict__ B, int ldb, long long zsB,
            const float* __restrict__ bias,
            TC* __restrict__ C, int ldc, long long zsC,
            int M, int N, int K, int act)
{
  A += (long long)blockIdx.z * zsA;
  B += (long long)blockIdx.z * zsB;
  C += (long long)blockIdx.z * zsC;
  __shared__ float As[64][17];
  __shared__ float Bs[16][64];
  const int tid = threadIdx.x;
  const int tx = tid & 15, ty = tid >> 4;
  const int bm = blockIdx.x * 64, bn = blockIdx.y * 64;
  float acc[4][4] = {};
  for (int k0 = 0; k0 < K; k0 += 16) {
#pragma unroll
    for (int i = 0; i < 4; i++) {
      int lin = tid + i * 256;
      int m = lin >> 4, kk = lin & 15;
      int gm = bm + m;
      As[m][kk] = (gm < M) ? ldf(&A[(size_t)gm * lda + k0 + kk]) : 0.f;
      int kb = lin >> 6, nb = lin & 63;
      Bs[kb][nb] = B[(size_t)(k0 + kb) * ldb + bn + nb];
    }
    __syncthreads();
#pragma unroll
    for (int kk = 0; kk < 16; kk++) {
      float a[4], b[4];
#pragma unroll
      for (int i = 0; i < 4; i++) a[i] = As[ty * 4 + i][kk];
#pragma unroll
      for (int j = 0; j < 4; j++) b[j] = Bs[kk][tx * 4 + j];
#pragma unroll
      for (int i = 0; i < 4; i++)
#pragma unroll
        for (int j = 0; j < 4; j++)
          acc[i][j] = fmaf(a[i], b[j], acc[i][j]);
    }
    __syncthreads();
  }
#pragma unroll
  for (int i = 0; i < 4; i++) {
    int gm = bm + ty * 4 + i;
    if (gm < M) {
#pragma unroll
      for (int j = 0; j < 4; j++) {
        int gn = bn + tx * 4 + j;
        float v = acc[i][j];
        if (bias) v += bias[gn];
        if (act == 1) v = fmaxf(v, 0.f);
        stf(&C[(size_t)gm * ldc + gn], v);
      }
    }
  }
}

// fused bias: b_out[h*D+e] = sum_d b_in[h*D+d] * rel[h,d,e]
__global__ __launch_bounds__(512)
void bias_fuse(const float* __restrict__ b_in, const float* __restrict__ rel,
               float* __restrict__ b_out)
{
  int j = threadIdx.x;           // 0..511
  int h = j >> 7, e = j & 127;
  const float* bh = b_in + h * DH;
  const float* rh = rel + (size_t)h * DH * DH;
  float s = 0.f;
  for (int d = 0; d < DH; d++) s = fmaf(bh[d], rh[d * DH + e], s);
  b_out[j] = s;
}

// alpha[e,h] = dot(q[dst,h,:], kr[src,h,:]) * p_rel[h] * scale  (wave/edge)
template<typename T>
__global__ __launch_bounds__(256)
void edge_alpha(const int* __restrict__ ei, int E,
                const T* __restrict__ q, const T* __restrict__ kr,
                const float* __restrict__ p_rel, float scale,
                float* __restrict__ alpha)
{
  int edge = blockIdx.x * 4 + (threadIdx.x >> 6);
  int lane = threadIdx.x & 63;
  if (edge >= E) return;
  int src = ei[edge];
  int dst = ei[E + edge];
  float qv[8], kv[8];
  load8(q + (size_t)dst * HID, lane, qv);
  load8(kr + (size_t)src * HID, lane, kv);
  float s = 0.f;
#pragma unroll
  for (int i = 0; i < 8; i++) s = fmaf(qv[i], kv[i], s);
  s += __shfl_xor(s, 8);
  s += __shfl_xor(s, 4);
  s += __shfl_xor(s, 2);
  s += __shfl_xor(s, 1);
  int h = lane >> 4;
  if ((lane & 15) == 0) alpha[(size_t)edge * NHEAD + h] = s * p_rel[h] * scale;
}

// monotonic float<->uint encoding for atomicMax-based segment max
__device__ __forceinline__ unsigned enc_f(float f) {
  unsigned b = __float_as_uint(f);
  return (b & 0x80000000u) ? ~b : (b | 0x80000000u);
}
__device__ __forceinline__ float dec_f(unsigned k) {
  return (k & 0x80000000u) ? __uint_as_float(k & 0x7FFFFFFFu) : __uint_as_float(~k);
}

__global__ __launch_bounds__(256)
void seg_max(const float* __restrict__ alpha, const int* __restrict__ ei_dst,
             int E, unsigned* __restrict__ mx)
{
  int i = blockIdx.x * 256 + threadIdx.x;
  if (i >= E * NHEAD) return;
  int edge = i >> 2, h = i & 3;
  atomicMax(&mx[(size_t)ei_dst[edge] * NHEAD + h], enc_f(alpha[i]));
}

__global__ __launch_bounds__(256)
void seg_expsum(float* __restrict__ alpha, const int* __restrict__ ei_dst,
                int E, const unsigned* __restrict__ mx, float* __restrict__ sum)
{
  int i = blockIdx.x * 256 + threadIdx.x;
  if (i >= E * NHEAD) return;
  int edge = i >> 2, h = i & 3;
  int dst = ei_dst[edge];
  float m = dec_f(mx[(size_t)dst * NHEAD + h]);
  float e = expf(alpha[i] - m);
  alpha[i] = e;
  atomicAdd(&sum[(size_t)dst * NHEAD + h], e);
}

// out[dst,h,:] += (e/sum) * vr[src,h,:]   (wave per edge, fp32 accumulator)
template<typename T>
__global__ __launch_bounds__(256)
void seg_aggregate(const float* __restrict__ alpha, const int* __restrict__ ei,
                   int E, const T* __restrict__ vr,
                   const float* __restrict__ sum, float* __restrict__ out)
{
  int edge = blockIdx.x * 4 + (threadIdx.x >> 6);
  int lane = threadIdx.x & 63;
  if (edge >= E) return;
  int src = ei[edge];
  int dst = ei[E + edge];
  int h = lane >> 4;
  float w = alpha[(size_t)edge * NHEAD + h] /
            (sum[(size_t)dst * NHEAD + h] + 1e-16f);
  float vv[8];
  load8(vr + (size_t)src * HID, lane, vv);
  float* orow = out + (size_t)dst * HID + lane * 8;
#pragma unroll
  for (int i = 0; i < 8; i++) atomicAdd(&orow[i], w * vv[i]);
}

__global__ __launch_bounds__(256)
void gelu_inplace(float* __restrict__ x, long long n)
{
  long long i = (long long)blockIdx.x * 256 + threadIdx.x;
  if (i < n) {
    float v = x[i];
    x[i] = 0.5f * v * (1.f + erff(v * 0.70710678118654752f));
  }
}

// h[row,:] = relu(LN(sp*oplin + (2-sp)*h)) ; per-row mean/var over 512
template<typename T>
__global__ __launch_bounds__(256)
void skip_ln_relu(const T* __restrict__ oplin, T* __restrict__ h,
                  const float* __restrict__ skipv,
                  const float* __restrict__ g, const float* __restrict__ b,
                  int rows)
{
  int row = blockIdx.x;
  if (row >= rows) return;
  float sp = 1.f / (1.f + expf(-skipv[0]));
  const T* orow = oplin + (size_t)row * HID;
  T* hrow = h + (size_t)row * HID;
  int t = threadIdx.x;
  float t0 = sp * ldf(&orow[2 * t])     + (2.f - sp) * ldf(&hrow[2 * t]);
  float t1 = sp * ldf(&orow[2 * t + 1]) + (2.f - sp) * ldf(&hrow[2 * t + 1]);
  float s = t0 + t1, ss = t0 * t0 + t1 * t1;
#pragma unroll
  for (int off = 32; off; off >>= 1) {
    s += __shfl_down(s, off);
    ss += __shfl_down(ss, off);
  }
  __shared__ float sh[8];
  int wid = t >> 6, lane = t & 63;
  if (lane == 0) { sh[wid] = s; sh[4 + wid] = ss; }
  __syncthreads();
  if (t == 0) {
    float S = 0, SS = 0;
    for (int w = 0; w < 4; w++) { S += sh[w]; SS += sh[4 + w]; }
    sh[0] = S; sh[4] = SS;
  }
  __syncthreads();
  float mu = sh[0] * (1.f / 512.f);
  float var = sh[4] * (1.f / 512.f) - mu * mu;
  float inv = rsqrtf(var + 1e-5f);
  float y0 = (t0 - mu) * inv * g[2 * t] + b[2 * t];
  float y1 = (t1 - mu) * inv * g[2 * t + 1] + b[2 * t + 1];
  stf(&hrow[2 * t], fmaxf(y0, 0.f));
  stf(&hrow[2 * t + 1], fmaxf(y1, 0.f));
}

// ---------------------------------------------------------------------------
template<typename TA, typename TC>
static inline void launch_gemm(const TA* A, int lda, long long zsA,
                               const float* B, int ldb, long long zsB,
                               const float* bias, TC* C, int ldc, long long zsC,
                               int M, int N, int K, int act, int Z, hipStream_t s)
{
  dim3 grid((M + 63) / 64, N / 64, Z), block(256);
  gemm_k<TA, TC><<<grid, block, 0, s>>>(A, lda, zsA, B, ldb, zsB, bias,
                                        C, ldc, zsC, M, N, K, act);
}

// Returns false (before launching anything) if ws_size is insufficient.
template<typename T>
static bool run_all(void* const* d_in, void* d_out, void* d_ws, size_t ws_size,
                    hipStream_t stream)
{
  const float* x_paper  = (const float*)d_in[0];
  const float* x_author = (const float*)d_in[1];
  const float* Wp_paper = (const float*)d_in[2];
  const float* bp_paper = (const float*)d_in[3];
  const float* Wp_author= (const float*)d_in[4];
  const float* bp_author= (const float*)d_in[5];
  const float* Wk = (const float*)d_in[6];
  const float* bk = (const float*)d_in[7];
  const float* Wq = (const float*)d_in[8];
  const float* bq = (const float*)d_in[9];
  const float* Wv = (const float*)d_in[10];
  const float* bv = (const float*)d_in[11];
  const float* Wa = (const float*)d_in[12];
  const float* ba = (const float*)d_in[13];
  const float* skip = (const float*)d_in[14];
  const float* a_rel = (const float*)d_in[15];
  const float* m_rel = (const float*)d_in[16];
  const float* p_rel = (const float*)d_in[17];
  const float* ln_g = (const float*)d_in[18];
  const float* ln_b = (const float*)d_in[19];
  const float* W256 = (const float*)d_in[20];
  const float* b256 = (const float*)d_in[21];
  const float* W128 = (const float*)d_in[22];
  const float* b128 = (const float*)d_in[23];
  const int* ei_c = (const int*)d_in[24];
  const int* ei_w = (const int*)d_in[25];
  const int* ei_b = (const int*)d_in[26];
  float* out = (float*)d_out;

  const size_t NPe = (size_t)NP * HID, NAe = (size_t)NA * HID;
  char* w = (char*)d_ws;
  size_t off = 0;
  auto alloc = [&](size_t bytes) -> void* {
    void* p = (void*)(w + off);
    off += (bytes + 255) & ~(size_t)255;
    return p;
  };
  T* hb_p   = (T*)alloc(NPe * sizeof(T));
  T* hb_a   = (T*)alloc(NAe * sizeof(T));
  float* big_p = (float*)alloc(NPe * 4);   // q (as T) -> op (f32) -> h256 (f32)
  float* big_a = (float*)alloc(NAe * 4);
  T* krv_p  = (T*)alloc(NPe * sizeof(T));  // kr -> vr -> oplin
  T* krv_a  = (T*)alloc(NAe * sizeof(T));
  float* Wf = (float*)alloc((size_t)12 * HID * HID * 4);  // [(l*3+r)*2+side]
  float* bf = (float*)alloc((size_t)12 * HID * 4);
  float* alphaP = (float*)alloc((size_t)(EC + EW) * NHEAD * 4);
  float* alphaA = (float*)alloc((size_t)EB * NHEAD * 4);
  unsigned* mxP = (unsigned*)alloc((size_t)NP * NHEAD * 4);
  float* sumP   = (float*)alloc((size_t)NP * NHEAD * 4);
  unsigned* mxA = (unsigned*)alloc((size_t)NA * NHEAD * 4);
  float* sumA   = (float*)alloc((size_t)NA * NHEAD * 4);
  if (off > ws_size) return false;

  const float scale = 0.08838834764831845f;  // 1/sqrt(128)

  // --- precompute fused relation weights/biases: Wf = Wk_blk @ a_rel, etc.
  for (int l = 0; l < NLAY; l++) {
    for (int r = 0; r < 3; r++) {
      int t = (r == 1) ? 1 : 0;  // src node type
      const float* Wk_lt = Wk + (size_t)(l * 2 + t) * HID * HID;
      const float* Wv_lt = Wv + (size_t)(l * 2 + t) * HID * HID;
      const float* bk_lt = bk + (size_t)(l * 2 + t) * HID;
      const float* bv_lt = bv + (size_t)(l * 2 + t) * HID;
      const float* ar = a_rel + (size_t)(l * 3 + r) * NHEAD * DH * DH;
      const float* mr = m_rel + (size_t)(l * 3 + r) * NHEAD * DH * DH;
      float* WfK = Wf + (size_t)((l * 3 + r) * 2 + 0) * HID * HID;
      float* WfV = Wf + (size_t)((l * 3 + r) * 2 + 1) * HID * HID;
      float* bfK = bf + (size_t)((l * 3 + r) * 2 + 0) * HID;
      float* bfV = bf + (size_t)((l * 3 + r) * 2 + 1) * HID;
      launch_gemm<float, float>(Wk_lt, HID, DH, ar, DH, DH * DH, nullptr,
                                WfK, HID, DH, HID, DH, DH, 0, NHEAD, stream);
      launch_gemm<float, float>(Wv_lt, HID, DH, mr, DH, DH * DH, nullptr,
                                WfV, HID, DH, HID, DH, DH, 0, NHEAD, stream);
      bias_fuse<<<1, 512, 0, stream>>>(bk_lt, ar, bfK);
      bias_fuse<<<1, 512, 0, stream>>>(bv_lt, mr, bfV);
    }
  }

  // --- input projections
  launch_gemm<float, T>(x_paper, INDIM, 0, Wp_paper, HID, 0, bp_paper,
                        hb_p, HID, 0, NP, HID, INDIM, 0, 1, stream);
  launch_gemm<float, T>(x_author, INDIM, 0, Wp_author, HID, 0, bp_author,
                        hb_a, HID, 0, NA, HID, INDIM, 0, 1, stream);

  for (int l = 0; l < NLAY; l++) {
    const float* Wq0 = Wq + (size_t)(l * 2 + 0) * HID * HID;
    const float* Wq1 = Wq + (size_t)(l * 2 + 1) * HID * HID;
    const float* bq0 = bq + (size_t)(l * 2 + 0) * HID;
    const float* bq1 = bq + (size_t)(l * 2 + 1) * HID;
    const float* prl = p_rel + (size_t)l * 3 * NHEAD;
    float* WfK0 = Wf + (size_t)((l * 3 + 0) * 2 + 0) * HID * HID;
    float* WfV0 = Wf + (size_t)((l * 3 + 0) * 2 + 1) * HID * HID;
    float* WfK1 = Wf + (size_t)((l * 3 + 1) * 2 + 0) * HID * HID;
    float* WfV1 = Wf + (size_t)((l * 3 + 1) * 2 + 1) * HID * HID;
    float* WfK2 = Wf + (size_t)((l * 3 + 2) * 2 + 0) * HID * HID;
    float* WfV2 = Wf + (size_t)((l * 3 + 2) * 2 + 1) * HID * HID;
    float* bfK0 = bf + (size_t)((l * 3 + 0) * 2 + 0) * HID;
    float* bfV0 = bf + (size_t)((l * 3 + 0) * 2 + 1) * HID;
    float* bfK1 = bf + (size_t)((l * 3 + 1) * 2 + 0) * HID;
    float* bfV1 = bf + (size_t)((l * 3 + 1) * 2 + 1) * HID;
    float* bfK2 = bf + (size_t)((l * 3 + 2) * 2 + 0) * HID;
    float* bfV2 = bf + (size_t)((l * 3 + 2) * 2 + 1) * HID;

    T* qp = (T*)big_p;
    T* qa = (T*)big_a;
    // plain Q
    launch_gemm<T, T>(hb_p, HID, 0, Wq0, HID, 0, bq0, qp, HID, 0, NP, HID, HID, 0, 1, stream);
    launch_gemm<T, T>(hb_a, HID, 0, Wq1, HID, 0, bq1, qa, HID, 0, NA, HID, HID, 0, 1, stream);
    // rel0 (cites, p->p): kr then alpha
    launch_gemm<T, T>(hb_p, HID, 0, WfK0, HID, 0, bfK0, krv_p, HID, 0, NP, HID, HID, 0, 1, stream);
    edge_alpha<T><<<dim3((EC + 3) / 4), 256, 0, stream>>>(ei_c, EC, qp, krv_p, prl + 0, scale, alphaP);
    // rel1 (writes, a->p): kr then alpha
    launch_gemm<T, T>(hb_a, HID, 0, WfK1, HID, 0, bfK1, krv_a, HID, 0, NA, HID, HID, 0, 1, stream);
    edge_alpha<T><<<dim3((EW + 3) / 4), 256, 0, stream>>>(ei_w, EW, qp, krv_a, prl + NHEAD, scale,
                                                          alphaP + (size_t)EC * NHEAD);
    // paper softmax (concat of rel0+rel1 per dst)
    hipMemsetAsync(mxP, 0, (size_t)NP * NHEAD * 4, stream);
    hipMemsetAsync(sumP, 0, (size_t)NP * NHEAD * 4, stream);
    seg_max<<<dim3((EC * NHEAD + 255) / 256), 256, 0, stream>>>(alphaP, ei_c + EC, EC, mxP);
    seg_max<<<dim3((EW * NHEAD + 255) / 256), 256, 0, stream>>>(alphaP + (size_t)EC * NHEAD, ei_w + EW, EW, mxP);
    seg_expsum<<<dim3((EC * NHEAD + 255) / 256), 256, 0, stream>>>(alphaP, ei_c + EC, EC, mxP, sumP);
    seg_expsum<<<dim3((EW * NHEAD + 255) / 256), 256, 0, stream>>>(alphaP + (size_t)EC * NHEAD, ei_w + EW, EW, mxP, sumP);
    // vr for rel0/rel1 (overwrite kr slabs; q slab becomes fp32 op)
    launch_gemm<T, T>(hb_p, HID, 0, WfV0, HID, 0, bfV0, krv_p, HID, 0, NP, HID, HID, 0, 1, stream);
    launch_gemm<T, T>(hb_a, HID, 0, WfV1, HID, 0, bfV1, krv_a, HID, 0, NA, HID, HID, 0, 1, stream);
    hipMemsetAsync(big_p, 0, NPe * 4, stream);
    seg_aggregate<T><<<dim3((EC + 3) / 4), 256, 0, stream>>>(alphaP, ei_c, EC, krv_p, sumP, big_p);
    seg_aggregate<T><<<dim3((EW + 3) / 4), 256, 0, stream>>>(alphaP + (size_t)EC * NHEAD, ei_w, EW, krv_a, sumP, big_p);
    // rel2 (written_by, p->a): kr, alpha (qa still live in big_a)
    launch_gemm<T, T>(hb_p, HID, 0, WfK2, HID, 0, bfK2, krv_p, HID, 0, NP, HID, HID, 0, 1, stream);
    edge_alpha<T><<<dim3((EB + 3) / 4), 256, 0, stream>>>(ei_b, EB, qa, krv_p, prl + 2 * NHEAD, scale, alphaA);
    hipMemsetAsync(mxA, 0, (size_t)NA * NHEAD * 4, stream);
    hipMemsetAsync(sumA, 0, (size_t)NA * NHEAD * 4, stream);
    seg_max<<<dim3((EB * NHEAD + 255) / 256), 256, 0, stream>>>(alphaA, ei_b + EB, EB, mxA);
    seg_expsum<<<dim3((EB * NHEAD + 255) / 256), 256, 0, stream>>>(alphaA, ei_b + EB, EB, mxA, sumA);
    launch_gemm<T, T>(hb_p, HID, 0, WfV2, HID, 0, bfV2, krv_p, HID, 0, NP, HID, HID, 0, 1, stream);
    hipMemsetAsync(big_a, 0, NAe * 4, stream);
    seg_aggregate<T><<<dim3((EB + 3) / 4), 256, 0, stream>>>(alphaA, ei_b, EB, krv_p, sumA, big_a);
    // gelu (exact) on fp32 accumulators
    gelu_inplace<<<dim3((int)((NPe + 255) / 256)), 256, 0, stream>>>(big_p, (long long)NPe);
    gelu_inplace<<<dim3((int)((NAe + 255) / 256)), 256, 0, stream>>>(big_a, (long long)NAe);
    // output linear -> oplin in krv slabs
    launch_gemm<float, T>(big_p, HID, 0, Wa + (size_t)(l * 2 + 0) * HID * HID, HID, 0,
                          ba + (size_t)(l * 2 + 0) * HID, krv_p, HID, 0, NP, HID, HID, 0, 1, stream);
    launch_gemm<float, T>(big_a, HID, 0, Wa + (size_t)(l * 2 + 1) * HID * HID, HID, 0,
                          ba + (size_t)(l * 2 + 1) * HID, krv_a, HID, 0, NA, HID, HID, 0, 1, stream);
    // skip + residual + LN + relu (in-place on h)
    skip_ln_relu<T><<<dim3(NP), 256, 0, stream>>>(krv_p, hb_p, skip + (l * 2 + 0),
                                                  ln_g + (size_t)l * HID, ln_b + (size_t)l * HID, NP);
    skip_ln_relu<T><<<dim3(NA), 256, 0, stream>>>(krv_a, hb_a, skip + (l * 2 + 1),
                                                  ln_g + (size_t)l * HID, ln_b + (size_t)l * HID, NA);
  }

  // final MLP
  launch_gemm<T, float>(hb_p, HID, 0, W256, 256, 0, b256, big_p, 256, 0, NP, 256, HID, 1, 1, stream);
  launch_gemm<float, float>(big_p, 256, 0, W128, 128, 0, b128, out, 128, 0, NP, 128, 256, 0, 1, stream);
  launch_gemm<T, float>(hb_a, HID, 0, W256, 256, 0, b256, big_a, 256, 0, NA, 256, HID, 1, 1, stream);
  launch_gemm<float, float>(big_a, 256, 0, W128, 128, 0, b128, out + (size_t)NP * 128, 128, 0, NA, 128, 256, 0, 1, stream);
  return true;
}

extern "C" void kernel_launch(void* const* d_in, const int* in_sizes, int n_in,
                              void* d_out, int out_size, void* d_ws, size_t ws_size,
                              hipStream_t stream)
{
  if (!run_all<float>(d_in, d_out, d_ws, ws_size, stream))
    run_all<bf16>(d_in, d_out, d_ws, ws_size, stream);
}

// Round 3
// 5962.348 us; speedup vs baseline: 2.3742x; 2.3742x over previous
//
#include <hip/hip_runtime.h>
#include <hip/hip_bf16.h>
#include <math.h>

#define NHEAD 4
#define DH 128
#define HID 512
#define NLAY 2
#define NP 30000
#define NA 10000
#define INDIM 768
#define EC 150000
#define EW 80000
#define EB 80000

typedef __hip_bfloat16 bf16;

__device__ __forceinline__ float ldf(const float* p){ return *p; }
__device__ __forceinline__ float ldf(const bf16* p){ return __bfloat162float(*p); }
__device__ __forceinline__ void stf(float* p, float v){ *p = v; }
__device__ __forceinline__ void stf(bf16* p, float v){ *p = __float2bfloat16(v); }

// load 8 consecutive elements starting at element index i8*8 (row 16B aligned)
__device__ __forceinline__ void load8(const float* __restrict__ p, int i8, float* o){
  const float4* q = (const float4*)p;
  float4 a = q[i8*2], b = q[i8*2+1];
  o[0]=a.x;o[1]=a.y;o[2]=a.z;o[3]=a.w;o[4]=b.x;o[5]=b.y;o[6]=b.z;o[7]=b.w;
}
__device__ __forceinline__ void load8(const bf16* __restrict__ p, int i8, float* o){
  uint4 r = ((const uint4*)p)[i8];
  o[0]=__uint_as_float(r.x<<16); o[1]=__uint_as_float(r.x&0xffff0000u);
  o[2]=__uint_as_float(r.y<<16); o[3]=__uint_as_float(r.y&0xffff0000u);
  o[4]=__uint_as_float(r.z<<16); o[5]=__uint_as_float(r.z&0xffff0000u);
  o[6]=__uint_as_float(r.w<<16); o[7]=__uint_as_float(r.w&0xffff0000u);
}

// ---------------------------------------------------------------------------
// Tiled GEMM: C[M,N] = A[M,K] @ B[K,N] (+bias) (+relu). B always fp32.
// blockIdx.z batches via element offsets zsA/zsB/zsC. N%64==0, K%16==0.
// ---------------------------------------------------------------------------
template<typename TA, typename TC>
__global__ __launch_bounds__(256)
void gemm_k(const TA* __restrict__ A, int lda, long long zsA,
            const float* __restrict__ B, int ldb, long long zsB,
            const float* __restrict__ bias,
            TC* __restrict__ C, int ldc, long long zsC,
            int M, int N, int K, int act)
{
  A += (long long)blockIdx.z * zsA;
  B += (long long)blockIdx.z * zsB;
  C += (long long)blockIdx.z * zsC;
  __shared__ float As[64][17];
  __shared__ float Bs[16][64];
  const int tid = threadIdx.x;
  const int tx = tid & 15, ty = tid >> 4;
  const int bm = blockIdx.x * 64, bn = blockIdx.y * 64;
  float acc[4][4] = {};
  for (int k0 = 0; k0 < K; k0 += 16) {
#pragma unroll
    for (int i = 0; i < 4; i++) {
      int lin = tid + i * 256;
      int m = lin >> 4, kk = lin & 15;
      int gm = bm + m;
      As[m][kk] = (gm < M) ? ldf(&A[(size_t)gm * lda + k0 + kk]) : 0.f;
      int kb = lin >> 6, nb = lin & 63;
      Bs[kb][nb] = B[(size_t)(k0 + kb) * ldb + bn + nb];
    }
    __syncthreads();
#pragma unroll
    for (int kk = 0; kk < 16; kk++) {
      float a[4], b[4];
#pragma unroll
      for (int i = 0; i < 4; i++) a[i] = As[ty * 4 + i][kk];
#pragma unroll
      for (int j = 0; j < 4; j++) b[j] = Bs[kk][tx * 4 + j];
#pragma unroll
      for (int i = 0; i < 4; i++)
#pragma unroll
        for (int j = 0; j < 4; j++)
          acc[i][j] = fmaf(a[i], b[j], acc[i][j]);
    }
    __syncthreads();
  }
#pragma unroll
  for (int i = 0; i < 4; i++) {
    int gm = bm + ty * 4 + i;
    if (gm < M) {
#pragma unroll
      for (int j = 0; j < 4; j++) {
        int gn = bn + tx * 4 + j;
        float v = acc[i][j];
        if (bias) v += bias[gn];
        if (act == 1) v = fmaxf(v, 0.f);
        stf(&C[(size_t)gm * ldc + gn], v);
      }
    }
  }
}

// fused bias: b_out[h*D+e] = sum_d b_in[h*D+d] * rel[h,d,e]
__global__ __launch_bounds__(512)
void bias_fuse(const float* __restrict__ b_in, const float* __restrict__ rel,
               float* __restrict__ b_out)
{
  int j = threadIdx.x;
  int h = j >> 7, e = j & 127;
  const float* bh = b_in + h * DH;
  const float* rh = rel + (size_t)h * DH * DH;
  float s = 0.f;
  for (int d = 0; d < DH; d++) s = fmaf(bh[d], rh[d * DH + e], s);
  b_out[j] = s;
}

// alpha[e,h] = dot(q[dst,h,:], kr[src,h,:]) * p_rel[h] * scale  (wave/edge)
template<typename T>
__global__ __launch_bounds__(256)
void edge_alpha(const int* __restrict__ ei, int E,
                const T* __restrict__ q, const T* __restrict__ kr,
                const float* __restrict__ p_rel, float scale,
                float* __restrict__ alpha)
{
  int edge = blockIdx.x * 4 + (threadIdx.x >> 6);
  int lane = threadIdx.x & 63;
  if (edge >= E) return;
  int src = ei[edge];
  int dst = ei[E + edge];
  float qv[8], kv[8];
  load8(q + (size_t)dst * HID, lane, qv);
  load8(kr + (size_t)src * HID, lane, kv);
  float s = 0.f;
#pragma unroll
  for (int i = 0; i < 8; i++) s = fmaf(qv[i], kv[i], s);
  s += __shfl_xor(s, 8);
  s += __shfl_xor(s, 4);
  s += __shfl_xor(s, 2);
  s += __shfl_xor(s, 1);
  int h = lane >> 4;
  if ((lane & 15) == 0) alpha[(size_t)edge * NHEAD + h] = s * p_rel[h] * scale;
}

// ------------------------- CSR build -----------------------------------
__global__ __launch_bounds__(256)
void build_hist(const int* __restrict__ ei_dst, int E, int* __restrict__ deg)
{
  int i = blockIdx.x * 256 + threadIdx.x;
  if (i < E) atomicAdd(&deg[ei_dst[i]], 1);
}

// single-workgroup exclusive scan; rowptr has n+1 entries
__global__ __launch_bounds__(256)
void excl_scan(const int* __restrict__ deg, int* __restrict__ rowptr, int n)
{
  __shared__ int sh[256];
  __shared__ int carry;
  if (threadIdx.x == 0) carry = 0;
  __syncthreads();
  for (int base = 0; base < n; base += 256) {
    int i = base + threadIdx.x;
    int v = (i < n) ? deg[i] : 0;
    sh[threadIdx.x] = v;
    __syncthreads();
#pragma unroll
    for (int off = 1; off < 256; off <<= 1) {
      int t = (threadIdx.x >= off) ? sh[threadIdx.x - off] : 0;
      __syncthreads();
      sh[threadIdx.x] += t;
      __syncthreads();
    }
    if (i < n) rowptr[i] = carry + sh[threadIdx.x] - v;
    __syncthreads();
    if (threadIdx.x == 0) carry += sh[255];
    __syncthreads();
  }
  if (threadIdx.x == 0) rowptr[n] = carry;
}

// scatter edges into CSR order; srcs packs (src | flag), eids = alpha row
__global__ __launch_bounds__(256)
void build_scatter(const int* __restrict__ ei, int E, int eid_base, int flag,
                   const int* __restrict__ rowptr, int* __restrict__ cursor,
                   int* __restrict__ eids, int* __restrict__ srcs)
{
  int e = blockIdx.x * 256 + threadIdx.x;
  if (e >= E) return;
  int src = ei[e];
  int dst = ei[E + e];
  int pos = rowptr[dst] + atomicAdd(&cursor[dst], 1);
  eids[pos] = eid_base + e;
  srcs[pos] = src | flag;
}

// ------------------- fused segment softmax + aggregate -------------------
// one 64-lane wave per destination node; head h = lane>>4, j = lane&15
template<typename T>
__global__ __launch_bounds__(256)
void csr_softmax_agg(const int* __restrict__ rowptr, const int* __restrict__ eids,
                     const int* __restrict__ srcs, int nnode,
                     const float* __restrict__ alpha,
                     const T* __restrict__ vr0, const T* __restrict__ vr1,
                     float* __restrict__ out)
{
  int node = blockIdx.x * 4 + (threadIdx.x >> 6);
  if (node >= nnode) return;
  int lane = threadIdx.x & 63;
  int h = lane >> 4, j = lane & 15;
  int beg = rowptr[node], end = rowptr[node + 1];
  // per-head max
  float mx = -INFINITY;
  for (int p = beg + j; p < end; p += 16)
    mx = fmaxf(mx, alpha[(size_t)eids[p] * NHEAD + h]);
  mx = fmaxf(mx, __shfl_xor(mx, 1));
  mx = fmaxf(mx, __shfl_xor(mx, 2));
  mx = fmaxf(mx, __shfl_xor(mx, 4));
  mx = fmaxf(mx, __shfl_xor(mx, 8));
  if (!isfinite(mx)) mx = 0.f;     // empty segment
  // per-head exp-sum
  float sm = 0.f;
  for (int p = beg + j; p < end; p += 16)
    sm += expf(alpha[(size_t)eids[p] * NHEAD + h] - mx);
  sm += __shfl_xor(sm, 1);
  sm += __shfl_xor(sm, 2);
  sm += __shfl_xor(sm, 4);
  sm += __shfl_xor(sm, 8);
  float inv = 1.f / (sm + 1e-16f);
  // weighted gather
  float acc[8] = {};
  for (int p = beg; p < end; ++p) {
    int se = srcs[p];
    int src = se & 0x3FFFFFFF;
    const T* table = (se & 0x40000000) ? vr1 : vr0;
    float w = expf(alpha[(size_t)eids[p] * NHEAD + h] - mx) * inv;
    float v[8];
    load8(table + (size_t)src * HID, lane, v);
#pragma unroll
    for (int i = 0; i < 8; i++) acc[i] = fmaf(w, v[i], acc[i]);
  }
  float* orow = out + (size_t)node * HID + lane * 8;
  ((float4*)orow)[0] = make_float4(acc[0], acc[1], acc[2], acc[3]);
  ((float4*)orow)[1] = make_float4(acc[4], acc[5], acc[6], acc[7]);
}

__global__ __launch_bounds__(256)
void gelu_inplace(float* __restrict__ x, long long n)
{
  long long i = (long long)blockIdx.x * 256 + threadIdx.x;
  if (i < n) {
    float v = x[i];
    x[i] = 0.5f * v * (1.f + erff(v * 0.70710678118654752f));
  }
}

// h[row,:] = relu(LN(sp*oplin + (2-sp)*h)) ; per-row mean/var over 512
template<typename T>
__global__ __launch_bounds__(256)
void skip_ln_relu(const T* __restrict__ oplin, T* __restrict__ h,
                  const float* __restrict__ skipv,
                  const float* __restrict__ g, const float* __restrict__ b,
                  int rows)
{
  int row = blockIdx.x;
  if (row >= rows) return;
  float sp = 1.f / (1.f + expf(-skipv[0]));
  const T* orow = oplin + (size_t)row * HID;
  T* hrow = h + (size_t)row * HID;
  int t = threadIdx.x;
  float t0 = sp * ldf(&orow[2 * t])     + (2.f - sp) * ldf(&hrow[2 * t]);
  float t1 = sp * ldf(&orow[2 * t + 1]) + (2.f - sp) * ldf(&hrow[2 * t + 1]);
  float s = t0 + t1, ss = t0 * t0 + t1 * t1;
#pragma unroll
  for (int off = 32; off; off >>= 1) {
    s += __shfl_down(s, off);
    ss += __shfl_down(ss, off);
  }
  __shared__ float sh[8];
  int wid = t >> 6, lane = t & 63;
  if (lane == 0) { sh[wid] = s; sh[4 + wid] = ss; }
  __syncthreads();
  if (t == 0) {
    float S = 0, SS = 0;
    for (int w = 0; w < 4; w++) { S += sh[w]; SS += sh[4 + w]; }
    sh[0] = S; sh[4] = SS;
  }
  __syncthreads();
  float mu = sh[0] * (1.f / 512.f);
  float var = sh[4] * (1.f / 512.f) - mu * mu;
  float inv = rsqrtf(var + 1e-5f);
  float y0 = (t0 - mu) * inv * g[2 * t] + b[2 * t];
  float y1 = (t1 - mu) * inv * g[2 * t + 1] + b[2 * t + 1];
  stf(&hrow[2 * t], fmaxf(y0, 0.f));
  stf(&hrow[2 * t + 1], fmaxf(y1, 0.f));
}

// ---------------------------------------------------------------------------
template<typename TA, typename TC>
static inline void launch_gemm(const TA* A, int lda, long long zsA,
                               const float* B, int ldb, long long zsB,
                               const float* bias, TC* C, int ldc, long long zsC,
                               int M, int N, int K, int act, int Z, hipStream_t s)
{
  dim3 grid((M + 63) / 64, N / 64, Z), block(256);
  gemm_k<TA, TC><<<grid, block, 0, s>>>(A, lda, zsA, B, ldb, zsB, bias,
                                        C, ldc, zsC, M, N, K, act);
}

template<typename T>
static bool run_all(void* const* d_in, void* d_out, void* d_ws, size_t ws_size,
                    hipStream_t stream)
{
  const float* x_paper  = (const float*)d_in[0];
  const float* x_author = (const float*)d_in[1];
  const float* Wp_paper = (const float*)d_in[2];
  const float* bp_paper = (const float*)d_in[3];
  const float* Wp_author= (const float*)d_in[4];
  const float* bp_author= (const float*)d_in[5];
  const float* Wk = (const float*)d_in[6];
  const float* bk = (const float*)d_in[7];
  const float* Wq = (const float*)d_in[8];
  const float* bq = (const float*)d_in[9];
  const float* Wv = (const float*)d_in[10];
  const float* bv = (const float*)d_in[11];
  const float* Wa = (const float*)d_in[12];
  const float* ba = (const float*)d_in[13];
  const float* skip = (const float*)d_in[14];
  const float* a_rel = (const float*)d_in[15];
  const float* m_rel = (const float*)d_in[16];
  const float* p_rel = (const float*)d_in[17];
  const float* ln_g = (const float*)d_in[18];
  const float* ln_b = (const float*)d_in[19];
  const float* W256 = (const float*)d_in[20];
  const float* b256 = (const float*)d_in[21];
  const float* W128 = (const float*)d_in[22];
  const float* b128 = (const float*)d_in[23];
  const int* ei_c = (const int*)d_in[24];
  const int* ei_w = (const int*)d_in[25];
  const int* ei_b = (const int*)d_in[26];
  float* out = (float*)d_out;

  const size_t NPe = (size_t)NP * HID, NAe = (size_t)NA * HID;
  char* w = (char*)d_ws;
  size_t off = 0;
  auto alloc = [&](size_t bytes) -> void* {
    void* p = (void*)(w + off);
    off += (bytes + 255) & ~(size_t)255;
    return p;
  };
  T* hb_p   = (T*)alloc(NPe * sizeof(T));
  T* hb_a   = (T*)alloc(NAe * sizeof(T));
  float* big_p = (float*)alloc(NPe * 4);   // q (as T) -> op (f32) -> h256 (f32)
  float* big_a = (float*)alloc(NAe * 4);
  T* krv_p  = (T*)alloc(NPe * sizeof(T));  // kr -> vr -> oplin
  T* krv_a  = (T*)alloc(NAe * sizeof(T));
  float* Wf = (float*)alloc((size_t)12 * HID * HID * 4);  // [(l*3+r)*2+side]
  float* bf = (float*)alloc((size_t)12 * HID * 4);
  float* alphaP = (float*)alloc((size_t)(EC + EW) * NHEAD * 4);
  float* alphaA = (float*)alloc((size_t)EB * NHEAD * 4);
  int* rowptrP = (int*)alloc((size_t)(NP + 1) * 4);
  int* degP    = (int*)alloc((size_t)NP * 4);          // reused as cursor
  int* eidsP   = (int*)alloc((size_t)(EC + EW) * 4);
  int* srcsP   = (int*)alloc((size_t)(EC + EW) * 4);
  int* rowptrA = (int*)alloc((size_t)(NA + 1) * 4);
  int* degA    = (int*)alloc((size_t)NA * 4);
  int* eidsA   = (int*)alloc((size_t)EB * 4);
  int* srcsA   = (int*)alloc((size_t)EB * 4);
  if (off > ws_size) return false;

  const float scale = 0.08838834764831845f;  // 1/sqrt(128)

  // --- CSR build (edges are layer-invariant: build once) ---
  hipMemsetAsync(degP, 0, (size_t)NP * 4, stream);
  hipMemsetAsync(degA, 0, (size_t)NA * 4, stream);
  build_hist<<<dim3((EC + 255) / 256), 256, 0, stream>>>(ei_c + EC, EC, degP);
  build_hist<<<dim3((EW + 255) / 256), 256, 0, stream>>>(ei_w + EW, EW, degP);
  build_hist<<<dim3((EB + 255) / 256), 256, 0, stream>>>(ei_b + EB, EB, degA);
  excl_scan<<<1, 256, 0, stream>>>(degP, rowptrP, NP);
  excl_scan<<<1, 256, 0, stream>>>(degA, rowptrA, NA);
  hipMemsetAsync(degP, 0, (size_t)NP * 4, stream);
  hipMemsetAsync(degA, 0, (size_t)NA * 4, stream);
  build_scatter<<<dim3((EC + 255) / 256), 256, 0, stream>>>(ei_c, EC, 0, 0,
      rowptrP, degP, eidsP, srcsP);
  build_scatter<<<dim3((EW + 255) / 256), 256, 0, stream>>>(ei_w, EW, EC, 0x40000000,
      rowptrP, degP, eidsP, srcsP);
  build_scatter<<<dim3((EB + 255) / 256), 256, 0, stream>>>(ei_b, EB, 0, 0,
      rowptrA, degA, eidsA, srcsA);

  // --- precompute fused relation weights/biases: Wf = Wk_blk @ a_rel, etc.
  for (int l = 0; l < NLAY; l++) {
    for (int r = 0; r < 3; r++) {
      int t = (r == 1) ? 1 : 0;  // src node type
      const float* Wk_lt = Wk + (size_t)(l * 2 + t) * HID * HID;
      const float* Wv_lt = Wv + (size_t)(l * 2 + t) * HID * HID;
      const float* bk_lt = bk + (size_t)(l * 2 + t) * HID;
      const float* bv_lt = bv + (size_t)(l * 2 + t) * HID;
      const float* ar = a_rel + (size_t)(l * 3 + r) * NHEAD * DH * DH;
      const float* mr = m_rel + (size_t)(l * 3 + r) * NHEAD * DH * DH;
      float* WfK = Wf + (size_t)((l * 3 + r) * 2 + 0) * HID * HID;
      float* WfV = Wf + (size_t)((l * 3 + r) * 2 + 1) * HID * HID;
      float* bfK = bf + (size_t)((l * 3 + r) * 2 + 0) * HID;
      float* bfV = bf + (size_t)((l * 3 + r) * 2 + 1) * HID;
      launch_gemm<float, float>(Wk_lt, HID, DH, ar, DH, DH * DH, nullptr,
                                WfK, HID, DH, HID, DH, DH, 0, NHEAD, stream);
      launch_gemm<float, float>(Wv_lt, HID, DH, mr, DH, DH * DH, nullptr,
                                WfV, HID, DH, HID, DH, DH, 0, NHEAD, stream);
      bias_fuse<<<1, 512, 0, stream>>>(bk_lt, ar, bfK);
      bias_fuse<<<1, 512, 0, stream>>>(bv_lt, mr, bfV);
    }
  }

  // --- input projections
  launch_gemm<float, T>(x_paper, INDIM, 0, Wp_paper, HID, 0, bp_paper,
                        hb_p, HID, 0, NP, HID, INDIM, 0, 1, stream);
  launch_gemm<float, T>(x_author, INDIM, 0, Wp_author, HID, 0, bp_author,
                        hb_a, HID, 0, NA, HID, INDIM, 0, 1, stream);

  for (int l = 0; l < NLAY; l++) {
    const float* Wq0 = Wq + (size_t)(l * 2 + 0) * HID * HID;
    const float* Wq1 = Wq + (size_t)(l * 2 + 1) * HID * HID;
    const float* bq0 = bq + (size_t)(l * 2 + 0) * HID;
    const float* bq1 = bq + (size_t)(l * 2 + 1) * HID;
    const float* prl = p_rel + (size_t)l * 3 * NHEAD;
    float* WfK0 = Wf + (size_t)((l * 3 + 0) * 2 + 0) * HID * HID;
    float* WfV0 = Wf + (size_t)((l * 3 + 0) * 2 + 1) * HID * HID;
    float* WfK1 = Wf + (size_t)((l * 3 + 1) * 2 + 0) * HID * HID;
    float* WfV1 = Wf + (size_t)((l * 3 + 1) * 2 + 1) * HID * HID;
    float* WfK2 = Wf + (size_t)((l * 3 + 2) * 2 + 0) * HID * HID;
    float* WfV2 = Wf + (size_t)((l * 3 + 2) * 2 + 1) * HID * HID;
    float* bfK0 = bf + (size_t)((l * 3 + 0) * 2 + 0) * HID;
    float* bfV0 = bf + (size_t)((l * 3 + 0) * 2 + 1) * HID;
    float* bfK1 = bf + (size_t)((l * 3 + 1) * 2 + 0) * HID;
    float* bfV1 = bf + (size_t)((l * 3 + 1) * 2 + 1) * HID;
    float* bfK2 = bf + (size_t)((l * 3 + 2) * 2 + 0) * HID;
    float* bfV2 = bf + (size_t)((l * 3 + 2) * 2 + 1) * HID;

    T* qp = (T*)big_p;
    T* qa = (T*)big_a;
    // plain Q
    launch_gemm<T, T>(hb_p, HID, 0, Wq0, HID, 0, bq0, qp, HID, 0, NP, HID, HID, 0, 1, stream);
    launch_gemm<T, T>(hb_a, HID, 0, Wq1, HID, 0, bq1, qa, HID, 0, NA, HID, HID, 0, 1, stream);
    // rel0 (cites, p->p): kr then alpha
    launch_gemm<T, T>(hb_p, HID, 0, WfK0, HID, 0, bfK0, krv_p, HID, 0, NP, HID, HID, 0, 1, stream);
    edge_alpha<T><<<dim3((EC + 3) / 4), 256, 0, stream>>>(ei_c, EC, qp, krv_p, prl + 0, scale, alphaP);
    // rel1 (writes, a->p): kr then alpha
    launch_gemm<T, T>(hb_a, HID, 0, WfK1, HID, 0, bfK1, krv_a, HID, 0, NA, HID, HID, 0, 1, stream);
    edge_alpha<T><<<dim3((EW + 3) / 4), 256, 0, stream>>>(ei_w, EW, qp, krv_a, prl + NHEAD, scale,
                                                          alphaP + (size_t)EC * NHEAD);
    // vr for rel0/rel1 (overwrite kr slabs)
    launch_gemm<T, T>(hb_p, HID, 0, WfV0, HID, 0, bfV0, krv_p, HID, 0, NP, HID, HID, 0, 1, stream);
    launch_gemm<T, T>(hb_a, HID, 0, WfV1, HID, 0, bfV1, krv_a, HID, 0, NA, HID, HID, 0, 1, stream);
    // fused softmax+aggregate over paper destinations (writes big_p fully)
    csr_softmax_agg<T><<<dim3((NP + 3) / 4), 256, 0, stream>>>(
        rowptrP, eidsP, srcsP, NP, alphaP, krv_p, krv_a, big_p);
    // rel2 (written_by, p->a): kr, alpha (qa still live in big_a)
    launch_gemm<T, T>(hb_p, HID, 0, WfK2, HID, 0, bfK2, krv_p, HID, 0, NP, HID, HID, 0, 1, stream);
    edge_alpha<T><<<dim3((EB + 3) / 4), 256, 0, stream>>>(ei_b, EB, qa, krv_p, prl + 2 * NHEAD, scale, alphaA);
    launch_gemm<T, T>(hb_p, HID, 0, WfV2, HID, 0, bfV2, krv_p, HID, 0, NP, HID, HID, 0, 1, stream);
    csr_softmax_agg<T><<<dim3((NA + 3) / 4), 256, 0, stream>>>(
        rowptrA, eidsA, srcsA, NA, alphaA, krv_p, krv_p, big_a);
    // gelu (exact) on fp32 accumulators
    gelu_inplace<<<dim3((int)((NPe + 255) / 256)), 256, 0, stream>>>(big_p, (long long)NPe);
    gelu_inplace<<<dim3((int)((NAe + 255) / 256)), 256, 0, stream>>>(big_a, (long long)NAe);
    // output linear -> oplin in krv slabs
    launch_gemm<float, T>(big_p, HID, 0, Wa + (size_t)(l * 2 + 0) * HID * HID, HID, 0,
                          ba + (size_t)(l * 2 + 0) * HID, krv_p, HID, 0, NP, HID, HID, 0, 1, stream);
    launch_gemm<float, T>(big_a, HID, 0, Wa + (size_t)(l * 2 + 1) * HID * HID, HID, 0,
                          ba + (size_t)(l * 2 + 1) * HID, krv_a, HID, 0, NA, HID, HID, 0, 1, stream);
    // skip + residual + LN + relu (in-place on h)
    skip_ln_relu<T><<<dim3(NP), 256, 0, stream>>>(krv_p, hb_p, skip + (l * 2 + 0),
                                                  ln_g + (size_t)l * HID, ln_b + (size_t)l * HID, NP);
    skip_ln_relu<T><<<dim3(NA), 256, 0, stream>>>(krv_a, hb_a, skip + (l * 2 + 1),
                                                  ln_g + (size_t)l * HID, ln_b + (size_t)l * HID, NA);
  }

  // final MLP
  launch_gemm<T, float>(hb_p, HID, 0, W256, 256, 0, b256, big_p, 256, 0, NP, 256, HID, 1, 1, stream);
  launch_gemm<float, float>(big_p, 256, 0, W128, 128, 0, b128, out, 128, 0, NP, 128, 256, 0, 1, stream);
  launch_gemm<T, float>(hb_a, HID, 0, W256, 256, 0, b256, big_a, 256, 0, NA, 256, HID, 1, 1, stream);
  launch_gemm<float, float>(big_a, 256, 0, W128, 128, 0, b128, out + (size_t)NP * 128, 128, 0, NA, 128, 256, 0, 1, stream);
  return true;
}

extern "C" void kernel_launch(void* const* d_in, const int* in_sizes, int n_in,
                              void* d_out, int out_size, void* d_ws, size_t ws_size,
                              hipStream_t stream)
{
  if (!run_all<float>(d_in, d_out, d_ws, ws_size, stream))
    run_all<bf16>(d_in, d_out, d_ws, ws_size, stream);
}

// Round 4
// 1687.465 us; speedup vs baseline: 8.3887x; 3.5333x over previous
//
#include <hip/hip_runtime.h>
#include <hip/hip_bf16.h>
#include <math.h>

#define NHEAD 4
#define DH 128
#define HID 512
#define NLAY 2
#define NP 30000
#define NA 10000
#define INDIM 768
#define EC 150000
#define EW 80000
#define EB 80000

typedef __hip_bfloat16 bf16;
typedef __attribute__((ext_vector_type(8))) short bf16x8;
typedef __attribute__((ext_vector_type(4))) float f32x4;

__device__ __forceinline__ void stf(float* p, float v){ *p = v; }
__device__ __forceinline__ void stf(bf16* p, float v){ *p = __float2bfloat16(v); }
__device__ __forceinline__ unsigned short f2bu(float f){ bf16 t = __float2bfloat16(f); return *(unsigned short*)&t; }
__device__ __forceinline__ float bu2f(unsigned short u){ return __uint_as_float((unsigned)u << 16); }

// load 8 consecutive bf16 at element offset i8*8 (16B aligned)
__device__ __forceinline__ void load8b(const bf16* __restrict__ p, int i8, float* o){
  uint4 r = ((const uint4*)p)[i8];
  o[0]=__uint_as_float(r.x<<16); o[1]=__uint_as_float(r.x&0xffff0000u);
  o[2]=__uint_as_float(r.y<<16); o[3]=__uint_as_float(r.y&0xffff0000u);
  o[4]=__uint_as_float(r.z<<16); o[5]=__uint_as_float(r.z&0xffff0000u);
  o[6]=__uint_as_float(r.w<<16); o[7]=__uint_as_float(r.w&0xffff0000u);
}

// ---------------------------------------------------------------------------
// MFMA bf16 GEMM: C[M,N] = A[M,K] @ Bt[N,K]^T (+bias fp32) (+relu)
// 128x128 tile, BK=64, 4 waves each owning 64x64 (4x4 frags of 16x16x32).
// LDS XOR-swizzled (k ^= (row&7)*8) on both write and read -> conflict-free.
// Requires N%128==0, K%64==0 (true for all shapes here). M guarded.
// ---------------------------------------------------------------------------
template<typename TC>
__global__ __launch_bounds__(256)
void mfma_gemm(const bf16* __restrict__ A, int lda,
               const bf16* __restrict__ Bt, int ldb,
               const float* __restrict__ bias,
               TC* __restrict__ C, int ldc,
               int M, int N, int K, int act)
{
  __shared__ __align__(16) short As[128 * 64];
  __shared__ __align__(16) short Bs[128 * 64];
  const int tid = threadIdx.x;
  const int lane = tid & 63, w = tid >> 6;
  const int brow = blockIdx.x * 128, bcol = blockIdx.y * 128;
  const int wr = w >> 1, wc = w & 1;
  f32x4 acc[4][4];
#pragma unroll
  for (int m = 0; m < 4; m++)
#pragma unroll
    for (int n = 0; n < 4; n++) acc[m][n] = (f32x4){0.f, 0.f, 0.f, 0.f};

  for (int k0 = 0; k0 < K; k0 += 64) {
#pragma unroll
    for (int i = 0; i < 4; i++) {
      int chunk = tid + i * 256;            // 0..1023: 128 rows x 8 chunks
      int row = chunk >> 3, kc = (chunk & 7) * 8;
      int sw = (row & 7) << 3;
      int grow = brow + row; grow = grow < M ? grow : M - 1;
      uint4 va = *(const uint4*)(A + (size_t)grow * lda + k0 + kc);
      *(uint4*)(As + row * 64 + (kc ^ sw)) = va;
      uint4 vb = *(const uint4*)(Bt + (size_t)(bcol + row) * ldb + k0 + kc);
      *(uint4*)(Bs + row * 64 + (kc ^ sw)) = vb;
    }
    __syncthreads();
#pragma unroll
    for (int kk = 0; kk < 2; kk++) {
      const int ke = kk * 32 + (lane >> 4) * 8;
      bf16x8 af[4], bq[4];
#pragma unroll
      for (int m = 0; m < 4; m++) {
        int row = wr * 64 + m * 16 + (lane & 15);
        af[m] = *(const bf16x8*)(As + row * 64 + (ke ^ ((row & 7) << 3)));
      }
#pragma unroll
      for (int n = 0; n < 4; n++) {
        int col = wc * 64 + n * 16 + (lane & 15);
        bq[n] = *(const bf16x8*)(Bs + col * 64 + (ke ^ ((col & 7) << 3)));
      }
#pragma unroll
      for (int m = 0; m < 4; m++)
#pragma unroll
        for (int n = 0; n < 4; n++)
          acc[m][n] = __builtin_amdgcn_mfma_f32_16x16x32_bf16(af[m], bq[n], acc[m][n], 0, 0, 0);
    }
    __syncthreads();
  }
#pragma unroll
  for (int m = 0; m < 4; m++) {
    int gr0 = brow + wr * 64 + m * 16 + (lane >> 4) * 4;
#pragma unroll
    for (int n = 0; n < 4; n++) {
      int gc = bcol + wc * 64 + n * 16 + (lane & 15);
      float bv = bias ? bias[gc] : 0.f;
#pragma unroll
      for (int r = 0; r < 4; r++) {
        int gr = gr0 + r;
        if (gr < M) {
          float v = acc[m][n][r] + bv;
          if (act) v = fmaxf(v, 0.f);
          stf(&C[(size_t)gr * ldc + gc], v);
        }
      }
    }
  }
}

// ---------------------------------------------------------------------------
// Weight preparation
// ---------------------------------------------------------------------------
struct FuseArgs {
  const float* W[12];    // [512,512] source (Wk or Wv block)
  const float* rel[12];  // [4,128,128] (a_rel or m_rel)
  const float* bin[12];  // [512] source bias
  float* out[12];        // [512,512] fused fp32
  bf16* outT[12];        // [512,512] fused, transposed, bf16
  float* bout[12];       // [512] fused bias
};

// fused weight: out[c][kin][h*128+e] = sum_d W[c][kin][h*128+d] * rel[c][h][d][e]
// z = c*4+h ; per-z GEMM M=512,N=128,K=128, 64x64 tiles
__global__ __launch_bounds__(256)
void gemm_fuse(FuseArgs fa)
{
  int c = blockIdx.z >> 2, h = blockIdx.z & 3;
  const float* A = fa.W[c] + h * 128;               // lda=512
  const float* B = fa.rel[c] + (size_t)h * 128 * 128;  // ldb=128
  float* C = fa.out[c] + h * 128;                   // ldc=512
  __shared__ float Ast[64][17];
  __shared__ float Bst[16][64];
  const int tid = threadIdx.x;
  const int tx = tid & 15, ty = tid >> 4;
  const int bm = blockIdx.x * 64, bn = blockIdx.y * 64;
  float acc[4][4] = {};
  for (int k0 = 0; k0 < 128; k0 += 16) {
#pragma unroll
    for (int i = 0; i < 4; i++) {
      int lin = tid + i * 256;
      int m = lin >> 4, kk = lin & 15;
      Ast[m][kk] = A[(size_t)(bm + m) * 512 + k0 + kk];
      int kb = lin >> 6, nb = lin & 63;
      Bst[kb][nb] = B[(size_t)(k0 + kb) * 128 + bn + nb];
    }
    __syncthreads();
#pragma unroll
    for (int kk = 0; kk < 16; kk++) {
      float a[4], b[4];
#pragma unroll
      for (int i = 0; i < 4; i++) a[i] = Ast[ty * 4 + i][kk];
#pragma unroll
      for (int j = 0; j < 4; j++) b[j] = Bst[kk][tx * 4 + j];
#pragma unroll
      for (int i = 0; i < 4; i++)
#pragma unroll
        for (int j = 0; j < 4; j++)
          acc[i][j] = fmaf(a[i], b[j], acc[i][j]);
    }
    __syncthreads();
  }
#pragma unroll
  for (int i = 0; i < 4; i++)
#pragma unroll
    for (int j = 0; j < 4; j++)
      C[(size_t)(bm + ty * 4 + i) * 512 + bn + tx * 4 + j] = acc[i][j];
}

// transpose 12x [512,512] fp32 -> bf16 transposed
__global__ __launch_bounds__(256)
void transpose12(FuseArgs fa)
{
  int c = blockIdx.z;
  const float* in = fa.out[c];
  bf16* o = fa.outT[c];
  __shared__ float t[32][33];
  int bn = blockIdx.x * 32, bk = blockIdx.y * 32;
  int x = threadIdx.x, y = threadIdx.y;
#pragma unroll
  for (int i = 0; i < 32; i += 8)
    t[y + i][x] = in[(size_t)(bk + y + i) * 512 + bn + x];
  __syncthreads();
#pragma unroll
  for (int i = 0; i < 32; i += 8)
    o[(size_t)(bn + y + i) * 512 + bk + x] = __float2bfloat16(t[x][y + i]);
}

// fused bias: bout[c][h*128+e] = sum_d bin[c][h*128+d] * rel[c][h][d][e]
__global__ __launch_bounds__(512)
void bias_fuse_all(FuseArgs fa)
{
  int c = blockIdx.x;
  int j = threadIdx.x;
  int h = j >> 7, e = j & 127;
  const float* bh = fa.bin[c] + h * DH;
  const float* rh = fa.rel[c] + (size_t)h * DH * DH;
  float s = 0.f;
  for (int d = 0; d < DH; d++) s = fmaf(bh[d], rh[d * DH + e], s);
  fa.bout[c][j] = s;
}

// generic [K,N] fp32 -> [N,K] bf16 transpose
__global__ __launch_bounds__(256)
void transpose_to_bf16(const float* __restrict__ in, bf16* __restrict__ out,
                       int K_, int N_)
{
  __shared__ float t[32][33];
  int bn = blockIdx.x * 32, bk = blockIdx.y * 32;
  int x = threadIdx.x, y = threadIdx.y;
#pragma unroll
  for (int i = 0; i < 32; i += 8) {
    int k = bk + y + i, n = bn + x;
    if (k < K_ && n < N_) t[y + i][x] = in[(size_t)k * N_ + n];
  }
  __syncthreads();
#pragma unroll
  for (int i = 0; i < 32; i += 8) {
    int n = bn + y + i, k = bk + x;
    if (n < N_ && k < K_) out[(size_t)n * K_ + k] = __float2bfloat16(t[x][y + i]);
  }
}

__global__ __launch_bounds__(256)
void f32_to_bf16(const float* __restrict__ x, bf16* __restrict__ y, long long n)
{
  long long i = ((long long)blockIdx.x * 256 + threadIdx.x) * 4;
  if (i >= n) return;
  float4 v = *(const float4*)(x + i);
  ushort4 o;
  o.x = f2bu(v.x); o.y = f2bu(v.y); o.z = f2bu(v.z); o.w = f2bu(v.w);
  *(ushort4*)(y + i) = o;
}

// ---------------------------------------------------------------------------
// Edge / attention kernels (bf16 features, fp32 math)
// ---------------------------------------------------------------------------
__global__ __launch_bounds__(256)
void edge_alpha(const int* __restrict__ ei, int E,
                const bf16* __restrict__ q, const bf16* __restrict__ kr,
                const float* __restrict__ p_rel, float scale,
                float* __restrict__ alpha)
{
  int edge = blockIdx.x * 4 + (threadIdx.x >> 6);
  int lane = threadIdx.x & 63;
  if (edge >= E) return;
  int src = ei[edge];
  int dst = ei[E + edge];
  float qv[8], kv[8];
  load8b(q + (size_t)dst * HID, lane, qv);
  load8b(kr + (size_t)src * HID, lane, kv);
  float s = 0.f;
#pragma unroll
  for (int i = 0; i < 8; i++) s = fmaf(qv[i], kv[i], s);
  s += __shfl_xor(s, 8);
  s += __shfl_xor(s, 4);
  s += __shfl_xor(s, 2);
  s += __shfl_xor(s, 1);
  int h = lane >> 4;
  if ((lane & 15) == 0) alpha[(size_t)edge * NHEAD + h] = s * p_rel[h] * scale;
}

__global__ __launch_bounds__(256)
void build_hist(const int* __restrict__ ei_dst, int E, int* __restrict__ deg)
{
  int i = blockIdx.x * 256 + threadIdx.x;
  if (i < E) atomicAdd(&deg[ei_dst[i]], 1);
}

__global__ __launch_bounds__(256)
void excl_scan(const int* __restrict__ deg, int* __restrict__ rowptr, int n)
{
  __shared__ int sh[256];
  __shared__ int carry;
  if (threadIdx.x == 0) carry = 0;
  __syncthreads();
  for (int base = 0; base < n; base += 256) {
    int i = base + threadIdx.x;
    int v = (i < n) ? deg[i] : 0;
    sh[threadIdx.x] = v;
    __syncthreads();
#pragma unroll
    for (int off = 1; off < 256; off <<= 1) {
      int t = (threadIdx.x >= off) ? sh[threadIdx.x - off] : 0;
      __syncthreads();
      sh[threadIdx.x] += t;
      __syncthreads();
    }
    if (i < n) rowptr[i] = carry + sh[threadIdx.x] - v;
    __syncthreads();
    if (threadIdx.x == 0) carry += sh[255];
    __syncthreads();
  }
  if (threadIdx.x == 0) rowptr[n] = carry;
}

__global__ __launch_bounds__(256)
void build_scatter(const int* __restrict__ ei, int E, int eid_base, int flag,
                   const int* __restrict__ rowptr, int* __restrict__ cursor,
                   int* __restrict__ eids, int* __restrict__ srcs)
{
  int e = blockIdx.x * 256 + threadIdx.x;
  if (e >= E) return;
  int src = ei[e];
  int dst = ei[E + e];
  int pos = rowptr[dst] + atomicAdd(&cursor[dst], 1);
  eids[pos] = eid_base + e;
  srcs[pos] = src | flag;
}

// one 64-lane wave per destination node; head h = lane>>4
__global__ __launch_bounds__(256)
void csr_softmax_agg(const int* __restrict__ rowptr, const int* __restrict__ eids,
                     const int* __restrict__ srcs, int nnode,
                     const float* __restrict__ alpha,
                     const bf16* __restrict__ vr0, const bf16* __restrict__ vr1,
                     float* __restrict__ out)
{
  int node = blockIdx.x * 4 + (threadIdx.x >> 6);
  if (node >= nnode) return;
  int lane = threadIdx.x & 63;
  int h = lane >> 4, j = lane & 15;
  int beg = rowptr[node], end = rowptr[node + 1];
  float mx = -INFINITY;
  for (int p = beg + j; p < end; p += 16)
    mx = fmaxf(mx, alpha[(size_t)eids[p] * NHEAD + h]);
  mx = fmaxf(mx, __shfl_xor(mx, 1));
  mx = fmaxf(mx, __shfl_xor(mx, 2));
  mx = fmaxf(mx, __shfl_xor(mx, 4));
  mx = fmaxf(mx, __shfl_xor(mx, 8));
  if (!isfinite(mx)) mx = 0.f;
  float sm = 0.f;
  for (int p = beg + j; p < end; p += 16)
    sm += expf(alpha[(size_t)eids[p] * NHEAD + h] - mx);
  sm += __shfl_xor(sm, 1);
  sm += __shfl_xor(sm, 2);
  sm += __shfl_xor(sm, 4);
  sm += __shfl_xor(sm, 8);
  float inv = 1.f / (sm + 1e-16f);
  float acc[8] = {};
  for (int p = beg; p < end; ++p) {
    int se = srcs[p];
    int src = se & 0x3FFFFFFF;
    const bf16* table = (se & 0x40000000) ? vr1 : vr0;
    float wgt = expf(alpha[(size_t)eids[p] * NHEAD + h] - mx) * inv;
    float v[8];
    load8b(table + (size_t)src * HID, lane, v);
#pragma unroll
    for (int i = 0; i < 8; i++) acc[i] = fmaf(wgt, v[i], acc[i]);
  }
  float* orow = out + (size_t)node * HID + lane * 8;
  ((float4*)orow)[0] = make_float4(acc[0], acc[1], acc[2], acc[3]);
  ((float4*)orow)[1] = make_float4(acc[4], acc[5], acc[6], acc[7]);
}

__global__ __launch_bounds__(256)
void gelu_to_bf16(const float* __restrict__ x, bf16* __restrict__ y, long long n)
{
  long long i = ((long long)blockIdx.x * 256 + threadIdx.x) * 4;
  if (i >= n) return;
  float4 v = *(const float4*)(x + i);
  ushort4 o;
  o.x = f2bu(0.5f * v.x * (1.f + erff(v.x * 0.70710678118654752f)));
  o.y = f2bu(0.5f * v.y * (1.f + erff(v.y * 0.70710678118654752f)));
  o.z = f2bu(0.5f * v.z * (1.f + erff(v.z * 0.70710678118654752f)));
  o.w = f2bu(0.5f * v.w * (1.f + erff(v.w * 0.70710678118654752f)));
  *(ushort4*)(y + i) = o;
}

// h[row,:] = relu(LN(sp*oplin + (2-sp)*h)) ; oplin fp32, h bf16 in/out
__global__ __launch_bounds__(256)
void skip_ln_relu_bf(const float* __restrict__ oplin, bf16* __restrict__ h,
                     const float* __restrict__ skipv,
                     const float* __restrict__ g, const float* __restrict__ b,
                     int rows)
{
  int row = blockIdx.x;
  if (row >= rows) return;
  float sp = 1.f / (1.f + expf(-skipv[0]));
  const float2* o2 = (const float2*)(oplin + (size_t)row * HID);
  ushort2* h2 = (ushort2*)(h + (size_t)row * HID);
  int t = threadIdx.x;
  float2 ov = o2[t];
  ushort2 hv = h2[t];
  float t0 = sp * ov.x + (2.f - sp) * bu2f(hv.x);
  float t1 = sp * ov.y + (2.f - sp) * bu2f(hv.y);
  float s = t0 + t1, ss = t0 * t0 + t1 * t1;
#pragma unroll
  for (int off = 32; off; off >>= 1) {
    s += __shfl_down(s, off);
    ss += __shfl_down(ss, off);
  }
  __shared__ float sh[8];
  int wid = t >> 6, lane = t & 63;
  if (lane == 0) { sh[wid] = s; sh[4 + wid] = ss; }
  __syncthreads();
  if (t == 0) {
    float S = 0, SS = 0;
    for (int wv = 0; wv < 4; wv++) { S += sh[wv]; SS += sh[4 + wv]; }
    sh[0] = S; sh[4] = SS;
  }
  __syncthreads();
  float mu = sh[0] * (1.f / 512.f);
  float var = sh[4] * (1.f / 512.f) - mu * mu;
  float inv = rsqrtf(var + 1e-5f);
  float y0 = (t0 - mu) * inv * g[2 * t] + b[2 * t];
  float y1 = (t1 - mu) * inv * g[2 * t + 1] + b[2 * t + 1];
  ushort2 o;
  o.x = f2bu(fmaxf(y0, 0.f));
  o.y = f2bu(fmaxf(y1, 0.f));
  h2[t] = o;
}

// ---------------------------------------------------------------------------
template<typename TC>
static inline void mgemm(const bf16* A, int lda, const bf16* Bt, int ldb,
                         const float* bias, TC* C, int ldc,
                         int M, int N, int K, int act, hipStream_t s)
{
  dim3 grid((M + 127) / 128, N / 128), block(256);
  mfma_gemm<TC><<<grid, block, 0, s>>>(A, lda, Bt, ldb, bias, C, ldc, M, N, K, act);
}

extern "C" void kernel_launch(void* const* d_in, const int* in_sizes, int n_in,
                              void* d_out, int out_size, void* d_ws, size_t ws_size,
                              hipStream_t stream)
{
  const float* x_paper  = (const float*)d_in[0];
  const float* x_author = (const float*)d_in[1];
  const float* Wp_paper = (const float*)d_in[2];
  const float* bp_paper = (const float*)d_in[3];
  const float* Wp_author= (const float*)d_in[4];
  const float* bp_author= (const float*)d_in[5];
  const float* Wk = (const float*)d_in[6];
  const float* bk = (const float*)d_in[7];
  const float* Wq = (const float*)d_in[8];
  const float* bq = (const float*)d_in[9];
  const float* Wv = (const float*)d_in[10];
  const float* bv = (const float*)d_in[11];
  const float* Wa = (const float*)d_in[12];
  const float* ba = (const float*)d_in[13];
  const float* skip = (const float*)d_in[14];
  const float* a_rel = (const float*)d_in[15];
  const float* m_rel = (const float*)d_in[16];
  const float* p_rel = (const float*)d_in[17];
  const float* ln_g = (const float*)d_in[18];
  const float* ln_b = (const float*)d_in[19];
  const float* W256 = (const float*)d_in[20];
  const float* b256 = (const float*)d_in[21];
  const float* W128 = (const float*)d_in[22];
  const float* b128 = (const float*)d_in[23];
  const int* ei_c = (const int*)d_in[24];
  const int* ei_w = (const int*)d_in[25];
  const int* ei_b = (const int*)d_in[26];
  float* out = (float*)d_out;

  const size_t NPe = (size_t)NP * HID, NAe = (size_t)NA * HID;
  const size_t HH = (size_t)HID * HID;
  char* w = (char*)d_ws;
  size_t off = 0;
  auto alloc = [&](size_t bytes) -> void* {
    void* p = (void*)(w + off);
    off += (bytes + 255) & ~(size_t)255;
    return p;
  };
  bf16* hb_p  = (bf16*)alloc(NPe * 2);
  bf16* hb_a  = (bf16*)alloc(NAe * 2);
  bf16* q_p   = (bf16*)alloc(NPe * 2);
  bf16* q_a   = (bf16*)alloc(NAe * 2);
  bf16* krv_p = (bf16*)alloc(NPe * 2);   // kr -> vr -> gelu(op) -> h256
  bf16* krv_a = (bf16*)alloc(NAe * 2);
  float* big_p = (float*)alloc(NPe * 4); // x_bf16 -> op acc -> oplin
  float* big_a = (float*)alloc(NAe * 4);
  float* Wf32 = (float*)alloc(12 * HH * 4);
  bf16* WfT   = (bf16*)alloc(12 * HH * 2);
  float* bff  = (float*)alloc(12 * HID * 4);
  bf16* WqT   = (bf16*)alloc(4 * HH * 2);
  bf16* WaT   = (bf16*)alloc(4 * HH * 2);
  bf16* W256T = (bf16*)alloc((size_t)HID * 256 * 2);
  bf16* W128T = (bf16*)alloc((size_t)256 * 128 * 2);
  bf16* WpTp  = (bf16*)alloc((size_t)INDIM * HID * 2);
  bf16* WpTa  = (bf16*)alloc((size_t)INDIM * HID * 2);
  float* alphaP = (float*)alloc((size_t)(EC + EW) * NHEAD * 4);
  float* alphaA = (float*)alloc((size_t)EB * NHEAD * 4);
  int* rowptrP = (int*)alloc((size_t)(NP + 1) * 4);
  int* degP    = (int*)alloc((size_t)NP * 4);
  int* eidsP   = (int*)alloc((size_t)(EC + EW) * 4);
  int* srcsP   = (int*)alloc((size_t)(EC + EW) * 4);
  int* rowptrA = (int*)alloc((size_t)(NA + 1) * 4);
  int* degA    = (int*)alloc((size_t)NA * 4);
  int* eidsA   = (int*)alloc((size_t)EB * 4);
  int* srcsA   = (int*)alloc((size_t)EB * 4);
  if (off > ws_size) return;

  const float scale = 0.08838834764831845f;  // 1/sqrt(128)

  // --- CSR build (edges are layer-invariant) ---
  hipMemsetAsync(degP, 0, (size_t)NP * 4, stream);
  hipMemsetAsync(degA, 0, (size_t)NA * 4, stream);
  build_hist<<<dim3((EC + 255) / 256), 256, 0, stream>>>(ei_c + EC, EC, degP);
  build_hist<<<dim3((EW + 255) / 256), 256, 0, stream>>>(ei_w + EW, EW, degP);
  build_hist<<<dim3((EB + 255) / 256), 256, 0, stream>>>(ei_b + EB, EB, degA);
  excl_scan<<<1, 256, 0, stream>>>(degP, rowptrP, NP);
  excl_scan<<<1, 256, 0, stream>>>(degA, rowptrA, NA);
  hipMemsetAsync(degP, 0, (size_t)NP * 4, stream);
  hipMemsetAsync(degA, 0, (size_t)NA * 4, stream);
  build_scatter<<<dim3((EC + 255) / 256), 256, 0, stream>>>(ei_c, EC, 0, 0,
      rowptrP, degP, eidsP, srcsP);
  build_scatter<<<dim3((EW + 255) / 256), 256, 0, stream>>>(ei_w, EW, EC, 0x40000000,
      rowptrP, degP, eidsP, srcsP);
  build_scatter<<<dim3((EB + 255) / 256), 256, 0, stream>>>(ei_b, EB, 0, 0,
      rowptrA, degA, eidsA, srcsA);

  // --- fused relation weights (one batched launch each) ---
  FuseArgs fa;
  for (int l = 0; l < NLAY; l++)
    for (int r = 0; r < 3; r++)
      for (int s = 0; s < 2; s++) {
        int c = (l * 3 + r) * 2 + s;
        int t = (r == 1) ? 1 : 0;
        fa.W[c]   = (s == 0 ? Wk : Wv) + (size_t)(l * 2 + t) * HH;
        fa.rel[c] = (s == 0 ? a_rel : m_rel) + (size_t)(l * 3 + r) * NHEAD * DH * DH;
        fa.bin[c] = (s == 0 ? bk : bv) + (size_t)(l * 2 + t) * HID;
        fa.out[c]  = Wf32 + (size_t)c * HH;
        fa.outT[c] = WfT + (size_t)c * HH;
        fa.bout[c] = bff + (size_t)c * HID;
      }
  gemm_fuse<<<dim3(8, 2, 48), 256, 0, stream>>>(fa);
  transpose12<<<dim3(16, 16, 12), dim3(32, 8), 0, stream>>>(fa);
  bias_fuse_all<<<dim3(12), 512, 0, stream>>>(fa);

  // --- plain weight transposes to bf16 ---
  auto tr = [&](const float* in, int K_, int N_, bf16* o) {
    dim3 g((N_ + 31) / 32, (K_ + 31) / 32), b(32, 8);
    transpose_to_bf16<<<g, b, 0, stream>>>(in, o, K_, N_);
  };
  for (int i = 0; i < 4; i++) {
    tr(Wq + (size_t)i * HH, HID, HID, WqT + (size_t)i * HH);
    tr(Wa + (size_t)i * HH, HID, HID, WaT + (size_t)i * HH);
  }
  tr(W256, HID, 256, W256T);
  tr(W128, 256, 128, W128T);
  tr(Wp_paper, INDIM, HID, WpTp);
  tr(Wp_author, INDIM, HID, WpTa);

  // --- input conversion + projection ---
  bf16* xb_p = (bf16*)big_p;
  bf16* xb_a = (bf16*)big_a;
  long long nxp = (long long)NP * INDIM, nxa = (long long)NA * INDIM;
  f32_to_bf16<<<dim3((int)((nxp / 4 + 255) / 256)), 256, 0, stream>>>(x_paper, xb_p, nxp);
  f32_to_bf16<<<dim3((int)((nxa / 4 + 255) / 256)), 256, 0, stream>>>(x_author, xb_a, nxa);
  mgemm<bf16>(xb_p, INDIM, WpTp, INDIM, bp_paper, hb_p, HID, NP, HID, INDIM, 0, stream);
  mgemm<bf16>(xb_a, INDIM, WpTa, INDIM, bp_author, hb_a, HID, NA, HID, INDIM, 0, stream);

  for (int l = 0; l < NLAY; l++) {
    const float* prl = p_rel + (size_t)l * 3 * NHEAD;
    int c0K = (l * 3 + 0) * 2, c0V = c0K + 1;
    int c1K = (l * 3 + 1) * 2, c1V = c1K + 1;
    int c2K = (l * 3 + 2) * 2, c2V = c2K + 1;
    // Q
    mgemm<bf16>(hb_p, HID, WqT + (size_t)(l * 2 + 0) * HH, HID, bq + (size_t)(l * 2 + 0) * HID,
                q_p, HID, NP, HID, HID, 0, stream);
    mgemm<bf16>(hb_a, HID, WqT + (size_t)(l * 2 + 1) * HH, HID, bq + (size_t)(l * 2 + 1) * HID,
                q_a, HID, NA, HID, HID, 0, stream);
    // rel0 (cites p->p): kr, alpha
    mgemm<bf16>(hb_p, HID, WfT + (size_t)c0K * HH, HID, bff + (size_t)c0K * HID,
                krv_p, HID, NP, HID, HID, 0, stream);
    edge_alpha<<<dim3((EC + 3) / 4), 256, 0, stream>>>(ei_c, EC, q_p, krv_p, prl + 0, scale, alphaP);
    // rel1 (writes a->p): kr, alpha
    mgemm<bf16>(hb_a, HID, WfT + (size_t)c1K * HH, HID, bff + (size_t)c1K * HID,
                krv_a, HID, NA, HID, HID, 0, stream);
    edge_alpha<<<dim3((EW + 3) / 4), 256, 0, stream>>>(ei_w, EW, q_p, krv_a, prl + NHEAD, scale,
                                                       alphaP + (size_t)EC * NHEAD);
    // vr0, vr1 then fused softmax+aggregate into big_p
    mgemm<bf16>(hb_p, HID, WfT + (size_t)c0V * HH, HID, bff + (size_t)c0V * HID,
                krv_p, HID, NP, HID, HID, 0, stream);
    mgemm<bf16>(hb_a, HID, WfT + (size_t)c1V * HH, HID, bff + (size_t)c1V * HID,
                krv_a, HID, NA, HID, HID, 0, stream);
    csr_softmax_agg<<<dim3((NP + 3) / 4), 256, 0, stream>>>(
        rowptrP, eidsP, srcsP, NP, alphaP, krv_p, krv_a, big_p);
    // rel2 (written_by p->a): kr, alpha, vr, aggregate into big_a
    mgemm<bf16>(hb_p, HID, WfT + (size_t)c2K * HH, HID, bff + (size_t)c2K * HID,
                krv_p, HID, NP, HID, HID, 0, stream);
    edge_alpha<<<dim3((EB + 3) / 4), 256, 0, stream>>>(ei_b, EB, q_a, krv_p, prl + 2 * NHEAD, scale, alphaA);
    mgemm<bf16>(hb_p, HID, WfT + (size_t)c2V * HH, HID, bff + (size_t)c2V * HID,
                krv_p, HID, NP, HID, HID, 0, stream);
    csr_softmax_agg<<<dim3((NA + 3) / 4), 256, 0, stream>>>(
        rowptrA, eidsA, srcsA, NA, alphaA, krv_p, krv_p, big_a);
    // gelu -> bf16
    gelu_to_bf16<<<dim3((int)((NPe / 4 + 255) / 256)), 256, 0, stream>>>(big_p, krv_p, (long long)NPe);
    gelu_to_bf16<<<dim3((int)((NAe / 4 + 255) / 256)), 256, 0, stream>>>(big_a, krv_a, (long long)NAe);
    // output linear (fp32 out)
    mgemm<float>(krv_p, HID, WaT + (size_t)(l * 2 + 0) * HH, HID, ba + (size_t)(l * 2 + 0) * HID,
                 big_p, HID, NP, HID, HID, 0, stream);
    mgemm<float>(krv_a, HID, WaT + (size_t)(l * 2 + 1) * HH, HID, ba + (size_t)(l * 2 + 1) * HID,
                 big_a, HID, NA, HID, HID, 0, stream);
    // skip + residual + LN + relu (bf16 h in/out, fp32 math)
    skip_ln_relu_bf<<<dim3(NP), 256, 0, stream>>>(big_p, hb_p, skip + (l * 2 + 0),
                                                  ln_g + (size_t)l * HID, ln_b + (size_t)l * HID, NP);
    skip_ln_relu_bf<<<dim3(NA), 256, 0, stream>>>(big_a, hb_a, skip + (l * 2 + 1),
                                                  ln_g + (size_t)l * HID, ln_b + (size_t)l * HID, NA);
  }

  // final MLP
  mgemm<bf16>(hb_p, HID, W256T, HID, b256, krv_p, 256, NP, 256, HID, 1, stream);
  mgemm<float>(krv_p, 256, W128T, 256, b128, out, 128, NP, 128, 256, 0, stream);
  mgemm<bf16>(hb_a, HID, W256T, HID, b256, krv_a, 256, NA, 256, HID, 1, stream);
  mgemm<float>(krv_a, 256, W128T, 256, b128, out + (size_t)NP * 128, 128, NA, 128, 256, 0, stream);
}

// Round 5
// 1442.477 us; speedup vs baseline: 9.8135x; 1.1698x over previous
//
#include <hip/hip_runtime.h>
#include <hip/hip_bf16.h>
#include <math.h>

#define NHEAD 4
#define DH 128
#define HID 512
#define NLAY 2
#define NP 30000
#define NA 10000
#define INDIM 768
#define EC 150000
#define EW 80000
#define EB 80000

typedef __hip_bfloat16 bf16;
typedef __attribute__((ext_vector_type(8))) short bf16x8;
typedef __attribute__((ext_vector_type(4))) float f32x4;

__device__ __forceinline__ void stf(float* p, float v){ *p = v; }
__device__ __forceinline__ void stf(bf16* p, float v){ *p = __float2bfloat16(v); }
__device__ __forceinline__ unsigned short f2bu(float f){ bf16 t = __float2bfloat16(f); return *(unsigned short*)&t; }
__device__ __forceinline__ float bu2f(unsigned short u){ return __uint_as_float((unsigned)u << 16); }

__device__ __forceinline__ void load8b(const bf16* __restrict__ p, int i8, float* o){
  uint4 r = ((const uint4*)p)[i8];
  o[0]=__uint_as_float(r.x<<16); o[1]=__uint_as_float(r.x&0xffff0000u);
  o[2]=__uint_as_float(r.y<<16); o[3]=__uint_as_float(r.y&0xffff0000u);
  o[4]=__uint_as_float(r.z<<16); o[5]=__uint_as_float(r.z&0xffff0000u);
  o[6]=__uint_as_float(r.w<<16); o[7]=__uint_as_float(r.w&0xffff0000u);
}

// async global->LDS, 16B per lane, wave-uniform LDS base + lane*16 (HW semantics)
__device__ __forceinline__ void gload16(const void* g, void* l) {
  __builtin_amdgcn_global_load_lds((const __attribute__((address_space(1))) void*)g,
                                   (__attribute__((address_space(3))) void*)l, 16, 0, 0);
}

// ---------------------------------------------------------------------------
// MFMA bf16 GEMM: C[M,N] = A[M,K] @ Bt[N,K]^T (+bias fp32) (+relu)
// 128x128 tile, BK=64, 4 waves x (4x4) frags of 16x16x32.
// Staging: global_load_lds 16B, pre-swizzled GLOBAL source (kc ^= (row&7)*8),
// linear LDS dest; ds_read uses the matching swizzle -> conflict-free.
// Requires N%128==0, K%64==0. M guarded (clamped duplicate loads, masked store).
// ---------------------------------------------------------------------------
template<typename TC>
__global__ __launch_bounds__(256)
void mfma_gemm(const bf16* __restrict__ A, int lda,
               const bf16* __restrict__ Bt, int ldb,
               const float* __restrict__ bias,
               TC* __restrict__ C, int ldc,
               int M, int N, int K, int act)
{
  __shared__ __align__(16) short As[128 * 64];
  __shared__ __align__(16) short Bs[128 * 64];
  const int tid = threadIdx.x;
  const int lane = tid & 63, w = tid >> 6;
  const int brow = blockIdx.x * 128, bcol = blockIdx.y * 128;
  const int wr = w >> 1, wc = w & 1;
  f32x4 acc[4][4];
#pragma unroll
  for (int m = 0; m < 4; m++)
#pragma unroll
    for (int n = 0; n < 4; n++) acc[m][n] = (f32x4){0.f, 0.f, 0.f, 0.f};

  for (int k0 = 0; k0 < K; k0 += 64) {
#pragma unroll
    for (int i = 0; i < 4; i++) {
      int chunk = i * 4 + w;                 // 0..15; wave-uniform
      int c_lin = chunk * 64 + lane;         // 16B-chunk index in tile
      int row = c_lin >> 3;
      int kc = ((c_lin & 7) ^ (row & 7)) * 8;  // inverse-swizzled source k
      int growA = brow + row; growA = growA < M ? growA : M - 1;
      gload16(A + (size_t)growA * lda + k0 + kc, As + chunk * 512);
      gload16(Bt + (size_t)(bcol + row) * ldb + k0 + kc, Bs + chunk * 512);
    }
    __syncthreads();
#pragma unroll
    for (int kk = 0; kk < 2; kk++) {
      const int ke = kk * 32 + (lane >> 4) * 8;
      bf16x8 af[4], bq[4];
#pragma unroll
      for (int m = 0; m < 4; m++) {
        int row = wr * 64 + m * 16 + (lane & 15);
        af[m] = *(const bf16x8*)(As + row * 64 + (ke ^ ((row & 7) << 3)));
      }
#pragma unroll
      for (int n = 0; n < 4; n++) {
        int col = wc * 64 + n * 16 + (lane & 15);
        bq[n] = *(const bf16x8*)(Bs + col * 64 + (ke ^ ((col & 7) << 3)));
      }
#pragma unroll
      for (int m = 0; m < 4; m++)
#pragma unroll
        for (int n = 0; n < 4; n++)
          acc[m][n] = __builtin_amdgcn_mfma_f32_16x16x32_bf16(af[m], bq[n], acc[m][n], 0, 0, 0);
    }
    __syncthreads();
  }
#pragma unroll
  for (int m = 0; m < 4; m++) {
    int gr0 = brow + wr * 64 + m * 16 + (lane >> 4) * 4;
#pragma unroll
    for (int n = 0; n < 4; n++) {
      int gc = bcol + wc * 64 + n * 16 + (lane & 15);
      float bv = bias ? bias[gc] : 0.f;
#pragma unroll
      for (int r = 0; r < 4; r++) {
        int gr = gr0 + r;
        if (gr < M) {
          float v = acc[m][n][r] + bv;
          if (act) v = fmaxf(v, 0.f);
          stf(&C[(size_t)gr * ldc + gc], v);
        }
      }
    }
  }
}

// ---------------------------------------------------------------------------
// Weight preparation
// ---------------------------------------------------------------------------
struct FuseArgs {
  const float* W[12];
  const float* rel[12];
  const float* bin[12];
  float* out[12];
  float* bout[12];
};
struct TrArgs {            // 20x [512,512] fp32 -> bf16 transposed
  const float* src[20];
  bf16* dst[20];
};

// fused weight: out[c][kin][h*128+e] = sum_d W[c][kin][h*128+d] * rel[c][h][d][e]
__global__ __launch_bounds__(256)
void gemm_fuse(FuseArgs fa)
{
  int c = blockIdx.z >> 2, h = blockIdx.z & 3;
  const float* A = fa.W[c] + h * 128;
  const float* B = fa.rel[c] + (size_t)h * 128 * 128;
  float* C = fa.out[c] + h * 128;
  __shared__ float Ast[64][17];
  __shared__ float Bst[16][64];
  const int tid = threadIdx.x;
  const int tx = tid & 15, ty = tid >> 4;
  const int bm = blockIdx.x * 64, bn = blockIdx.y * 64;
  float acc[4][4] = {};
  for (int k0 = 0; k0 < 128; k0 += 16) {
#pragma unroll
    for (int i = 0; i < 4; i++) {
      int lin = tid + i * 256;
      int m = lin >> 4, kk = lin & 15;
      Ast[m][kk] = A[(size_t)(bm + m) * 512 + k0 + kk];
      int kb = lin >> 6, nb = lin & 63;
      Bst[kb][nb] = B[(size_t)(k0 + kb) * 128 + bn + nb];
    }
    __syncthreads();
#pragma unroll
    for (int kk = 0; kk < 16; kk++) {
      float a[4], b[4];
#pragma unroll
      for (int i = 0; i < 4; i++) a[i] = Ast[ty * 4 + i][kk];
#pragma unroll
      for (int j = 0; j < 4; j++) b[j] = Bst[kk][tx * 4 + j];
#pragma unroll
      for (int i = 0; i < 4; i++)
#pragma unroll
        for (int j = 0; j < 4; j++)
          acc[i][j] = fmaf(a[i], b[j], acc[i][j]);
    }
    __syncthreads();
  }
#pragma unroll
  for (int i = 0; i < 4; i++)
#pragma unroll
    for (int j = 0; j < 4; j++)
      C[(size_t)(bm + ty * 4 + i) * 512 + bn + tx * 4 + j] = acc[i][j];
}

__global__ __launch_bounds__(256)
void transpose20(TrArgs ta)
{
  int c = blockIdx.z;
  const float* in = ta.src[c];
  bf16* o = ta.dst[c];
  __shared__ float t[32][33];
  int bn = blockIdx.x * 32, bk = blockIdx.y * 32;
  int x = threadIdx.x, y = threadIdx.y;
#pragma unroll
  for (int i = 0; i < 32; i += 8)
    t[y + i][x] = in[(size_t)(bk + y + i) * 512 + bn + x];
  __syncthreads();
#pragma unroll
  for (int i = 0; i < 32; i += 8)
    o[(size_t)(bn + y + i) * 512 + bk + x] = __float2bfloat16(t[x][y + i]);
}

__global__ __launch_bounds__(512)
void bias_fuse_all(FuseArgs fa)
{
  int c = blockIdx.x;
  int j = threadIdx.x;
  int h = j >> 7, e = j & 127;
  const float* bh = fa.bin[c] + h * DH;
  const float* rh = fa.rel[c] + (size_t)h * DH * DH;
  float s = 0.f;
  for (int d = 0; d < DH; d++) s = fmaf(bh[d], rh[d * DH + e], s);
  fa.bout[c][j] = s;
}

__global__ __launch_bounds__(256)
void transpose_to_bf16(const float* __restrict__ in, bf16* __restrict__ out,
                       int K_, int N_)
{
  __shared__ float t[32][33];
  int bn = blockIdx.x * 32, bk = blockIdx.y * 32;
  int x = threadIdx.x, y = threadIdx.y;
#pragma unroll
  for (int i = 0; i < 32; i += 8) {
    int k = bk + y + i, n = bn + x;
    if (k < K_ && n < N_) t[y + i][x] = in[(size_t)k * N_ + n];
  }
  __syncthreads();
#pragma unroll
  for (int i = 0; i < 32; i += 8) {
    int n = bn + y + i, k = bk + x;
    if (n < N_ && k < K_) out[(size_t)n * K_ + k] = __float2bfloat16(t[x][y + i]);
  }
}

__global__ __launch_bounds__(256)
void f32_to_bf16(const float* __restrict__ x, bf16* __restrict__ y, long long n)
{
  long long i = ((long long)blockIdx.x * 256 + threadIdx.x) * 4;
  if (i >= n) return;
  float4 v = *(const float4*)(x + i);
  ushort4 o;
  o.x = f2bu(v.x); o.y = f2bu(v.y); o.z = f2bu(v.z); o.w = f2bu(v.w);
  *(ushort4*)(y + i) = o;
}

// ---------------------------------------------------------------------------
// Edge / attention kernels
// ---------------------------------------------------------------------------
__global__ __launch_bounds__(256)
void edge_alpha(const int* __restrict__ ei, int E,
                const bf16* __restrict__ q, const bf16* __restrict__ kr,
                const float* __restrict__ p_rel, float scale,
                float* __restrict__ alpha)
{
  int edge = blockIdx.x * 4 + (threadIdx.x >> 6);
  int lane = threadIdx.x & 63;
  if (edge >= E) return;
  int src = ei[edge];
  int dst = ei[E + edge];
  float qv[8], kv[8];
  load8b(q + (size_t)dst * HID, lane, qv);
  load8b(kr + (size_t)src * HID, lane, kv);
  float s = 0.f;
#pragma unroll
  for (int i = 0; i < 8; i++) s = fmaf(qv[i], kv[i], s);
  s += __shfl_xor(s, 8);
  s += __shfl_xor(s, 4);
  s += __shfl_xor(s, 2);
  s += __shfl_xor(s, 1);
  int h = lane >> 4;
  if ((lane & 15) == 0) alpha[(size_t)edge * NHEAD + h] = s * p_rel[h] * scale;
}

__global__ __launch_bounds__(256)
void build_hist(const int* __restrict__ ei_dst, int E, int* __restrict__ deg)
{
  int i = blockIdx.x * 256 + threadIdx.x;
  if (i < E) atomicAdd(&deg[ei_dst[i]], 1);
}

// --------- hierarchical exclusive scan (3 phases) ---------
__global__ __launch_bounds__(256)
void scan_blk(const int* __restrict__ deg, int n, int* __restrict__ rowptr,
              int* __restrict__ bsum)
{
  __shared__ int sh[256];
  int t = threadIdx.x;
  int base = blockIdx.x * 1024 + t * 4;
  int v0 = 0, v1 = 0, v2 = 0, v3 = 0;
  if (base + 3 < n) {
    int4 v = *(const int4*)(deg + base);
    v0 = v.x; v1 = v.y; v2 = v.z; v3 = v.w;
  } else {
    if (base < n)     v0 = deg[base];
    if (base + 1 < n) v1 = deg[base + 1];
    if (base + 2 < n) v2 = deg[base + 2];
    if (base + 3 < n) v3 = deg[base + 3];
  }
  int s = v0 + v1 + v2 + v3;
  sh[t] = s;
  __syncthreads();
#pragma unroll
  for (int off = 1; off < 256; off <<= 1) {
    int tv = (t >= off) ? sh[t - off] : 0;
    __syncthreads();
    sh[t] += tv;
    __syncthreads();
  }
  int excl = sh[t] - s;
  if (t == 255) bsum[blockIdx.x] = sh[255];
  if (base < n)     rowptr[base] = excl;
  if (base + 1 < n) rowptr[base + 1] = excl + v0;
  if (base + 2 < n) rowptr[base + 2] = excl + v0 + v1;
  if (base + 3 < n) rowptr[base + 3] = excl + v0 + v1 + v2;
}

__global__ __launch_bounds__(64)
void scan_bsum(int* __restrict__ bsum, int nb, int* __restrict__ rowptr_end)
{
  int t = threadIdx.x;
  int v = (t < nb) ? bsum[t] : 0;
  int inc = v;
#pragma unroll
  for (int off = 1; off < 64; off <<= 1) {
    int o = __shfl_up(inc, off);
    if (t >= off) inc += o;
  }
  if (t < nb) bsum[t] = inc - v;
  if (t == nb - 1) *rowptr_end = inc;
}

__global__ __launch_bounds__(256)
void scan_add(int* __restrict__ rowptr, const int* __restrict__ bsum, int n)
{
  int add = bsum[blockIdx.x];
  if (add == 0) return;
  int i = blockIdx.x * 1024 + threadIdx.x * 4;
  if (i < n)     rowptr[i] += add;
  if (i + 1 < n) rowptr[i + 1] += add;
  if (i + 2 < n) rowptr[i + 2] += add;
  if (i + 3 < n) rowptr[i + 3] += add;
}

__global__ __launch_bounds__(256)
void build_scatter(const int* __restrict__ ei, int E, int eid_base, int flag,
                   const int* __restrict__ rowptr, int* __restrict__ cursor,
                   int* __restrict__ eids, int* __restrict__ srcs)
{
  int e = blockIdx.x * 256 + threadIdx.x;
  if (e >= E) return;
  int src = ei[e];
  int dst = ei[E + e];
  int pos = rowptr[dst] + atomicAdd(&cursor[dst], 1);
  eids[pos] = eid_base + e;
  srcs[pos] = src | flag;
}

// fused segment softmax + aggregate + exact gelu -> bf16 output row
__global__ __launch_bounds__(256)
void csr_softmax_agg(const int* __restrict__ rowptr, const int* __restrict__ eids,
                     const int* __restrict__ srcs, int nnode,
                     const float* __restrict__ alpha,
                     const bf16* __restrict__ vr0, const bf16* __restrict__ vr1,
                     bf16* __restrict__ outb)
{
  int node = blockIdx.x * 4 + (threadIdx.x >> 6);
  if (node >= nnode) return;
  int lane = threadIdx.x & 63;
  int h = lane >> 4, j = lane & 15;
  int beg = rowptr[node], end = rowptr[node + 1];
  float mx = -INFINITY;
  for (int p = beg + j; p < end; p += 16)
    mx = fmaxf(mx, alpha[(size_t)eids[p] * NHEAD + h]);
  mx = fmaxf(mx, __shfl_xor(mx, 1));
  mx = fmaxf(mx, __shfl_xor(mx, 2));
  mx = fmaxf(mx, __shfl_xor(mx, 4));
  mx = fmaxf(mx, __shfl_xor(mx, 8));
  if (!isfinite(mx)) mx = 0.f;
  float sm = 0.f;
  for (int p = beg + j; p < end; p += 16)
    sm += expf(alpha[(size_t)eids[p] * NHEAD + h] - mx);
  sm += __shfl_xor(sm, 1);
  sm += __shfl_xor(sm, 2);
  sm += __shfl_xor(sm, 4);
  sm += __shfl_xor(sm, 8);
  float inv = 1.f / (sm + 1e-16f);
  float acc[8] = {};
  for (int p = beg; p < end; ++p) {
    int se = srcs[p];
    int src = se & 0x3FFFFFFF;
    const bf16* table = (se & 0x40000000) ? vr1 : vr0;
    float wgt = expf(alpha[(size_t)eids[p] * NHEAD + h] - mx) * inv;
    float v[8];
    load8b(table + (size_t)src * HID, lane, v);
#pragma unroll
    for (int i = 0; i < 8; i++) acc[i] = fmaf(wgt, v[i], acc[i]);
  }
  // exact gelu + bf16 pack
  unsigned short g[8];
#pragma unroll
  for (int i = 0; i < 8; i++)
    g[i] = f2bu(0.5f * acc[i] * (1.f + erff(acc[i] * 0.70710678118654752f)));
  uint4 o;
  o.x = g[0] | ((unsigned)g[1] << 16);
  o.y = g[2] | ((unsigned)g[3] << 16);
  o.z = g[4] | ((unsigned)g[5] << 16);
  o.w = g[6] | ((unsigned)g[7] << 16);
  *(uint4*)(outb + (size_t)node * HID + lane * 8) = o;
}

// h[row,:] = relu(LN(sp*oplin + (2-sp)*h)) ; oplin fp32, h bf16 in/out
__global__ __launch_bounds__(256)
void skip_ln_relu_bf(const float* __restrict__ oplin, bf16* __restrict__ h,
                     const float* __restrict__ skipv,
                     const float* __restrict__ g, const float* __restrict__ b,
                     int rows)
{
  int row = blockIdx.x;
  if (row >= rows) return;
  float sp = 1.f / (1.f + expf(-skipv[0]));
  const float2* o2 = (const float2*)(oplin + (size_t)row * HID);
  ushort2* h2 = (ushort2*)(h + (size_t)row * HID);
  int t = threadIdx.x;
  float2 ov = o2[t];
  ushort2 hv = h2[t];
  float t0 = sp * ov.x + (2.f - sp) * bu2f(hv.x);
  float t1 = sp * ov.y + (2.f - sp) * bu2f(hv.y);
  float s = t0 + t1, ss = t0 * t0 + t1 * t1;
#pragma unroll
  for (int off = 32; off; off >>= 1) {
    s += __shfl_down(s, off);
    ss += __shfl_down(ss, off);
  }
  __shared__ float sh[8];
  int wid = t >> 6, lane = t & 63;
  if (lane == 0) { sh[wid] = s; sh[4 + wid] = ss; }
  __syncthreads();
  if (t == 0) {
    float S = 0, SS = 0;
    for (int wv = 0; wv < 4; wv++) { S += sh[wv]; SS += sh[4 + wv]; }
    sh[0] = S; sh[4] = SS;
  }
  __syncthreads();
  float mu = sh[0] * (1.f / 512.f);
  float var = sh[4] * (1.f / 512.f) - mu * mu;
  float inv = rsqrtf(var + 1e-5f);
  float y0 = (t0 - mu) * inv * g[2 * t] + b[2 * t];
  float y1 = (t1 - mu) * inv * g[2 * t + 1] + b[2 * t + 1];
  ushort2 o;
  o.x = f2bu(fmaxf(y0, 0.f));
  o.y = f2bu(fmaxf(y1, 0.f));
  h2[t] = o;
}

// ---------------------------------------------------------------------------
template<typename TC>
static inline void mgemm(const bf16* A, int lda, const bf16* Bt, int ldb,
                         const float* bias, TC* C, int ldc,
                         int M, int N, int K, int act, hipStream_t s)
{
  dim3 grid((M + 127) / 128, N / 128), block(256);
  mfma_gemm<TC><<<grid, block, 0, s>>>(A, lda, Bt, ldb, bias, C, ldc, M, N, K, act);
}

extern "C" void kernel_launch(void* const* d_in, const int* in_sizes, int n_in,
                              void* d_out, int out_size, void* d_ws, size_t ws_size,
                              hipStream_t stream)
{
  const float* x_paper  = (const float*)d_in[0];
  const float* x_author = (const float*)d_in[1];
  const float* Wp_paper = (const float*)d_in[2];
  const float* bp_paper = (const float*)d_in[3];
  const float* Wp_author= (const float*)d_in[4];
  const float* bp_author= (const float*)d_in[5];
  const float* Wk = (const float*)d_in[6];
  const float* bk = (const float*)d_in[7];
  const float* Wq = (const float*)d_in[8];
  const float* bq = (const float*)d_in[9];
  const float* Wv = (const float*)d_in[10];
  const float* bv = (const float*)d_in[11];
  const float* Wa = (const float*)d_in[12];
  const float* ba = (const float*)d_in[13];
  const float* skip = (const float*)d_in[14];
  const float* a_rel = (const float*)d_in[15];
  const float* m_rel = (const float*)d_in[16];
  const float* p_rel = (const float*)d_in[17];
  const float* ln_g = (const float*)d_in[18];
  const float* ln_b = (const float*)d_in[19];
  const float* W256 = (const float*)d_in[20];
  const float* b256 = (const float*)d_in[21];
  const float* W128 = (const float*)d_in[22];
  const float* b128 = (const float*)d_in[23];
  const int* ei_c = (const int*)d_in[24];
  const int* ei_w = (const int*)d_in[25];
  const int* ei_b = (const int*)d_in[26];
  float* out = (float*)d_out;

  const size_t NPe = (size_t)NP * HID, NAe = (size_t)NA * HID;
  const size_t HH = (size_t)HID * HID;
  char* w = (char*)d_ws;
  size_t off = 0;
  auto alloc = [&](size_t bytes) -> void* {
    void* p = (void*)(w + off);
    off += (bytes + 255) & ~(size_t)255;
    return p;
  };
  bf16* hb_p  = (bf16*)alloc(NPe * 2);
  bf16* hb_a  = (bf16*)alloc(NAe * 2);
  bf16* q_p   = (bf16*)alloc(NPe * 2);   // q -> gelu(op) -> h256
  bf16* q_a   = (bf16*)alloc(NAe * 2);
  bf16* krv_p = (bf16*)alloc(NPe * 2);   // kr -> vr
  bf16* krv_a = (bf16*)alloc(NAe * 2);
  float* big_p = (float*)alloc(NPe * 4); // x_bf16 -> oplin
  float* big_a = (float*)alloc(NAe * 4);
  float* Wf32 = (float*)alloc(12 * HH * 4);
  bf16* WfT   = (bf16*)alloc(12 * HH * 2);
  float* bff  = (float*)alloc(12 * HID * 4);
  bf16* WqT   = (bf16*)alloc(4 * HH * 2);
  bf16* WaT   = (bf16*)alloc(4 * HH * 2);
  bf16* W256T = (bf16*)alloc((size_t)HID * 256 * 2);
  bf16* W128T = (bf16*)alloc((size_t)256 * 128 * 2);
  bf16* WpTp  = (bf16*)alloc((size_t)INDIM * HID * 2);
  bf16* WpTa  = (bf16*)alloc((size_t)INDIM * HID * 2);
  float* alphaP = (float*)alloc((size_t)(EC + EW) * NHEAD * 4);
  float* alphaA = (float*)alloc((size_t)EB * NHEAD * 4);
  int* rowptrP = (int*)alloc((size_t)(NP + 1) * 4);
  int* degP    = (int*)alloc((size_t)NP * 4);
  int* eidsP   = (int*)alloc((size_t)(EC + EW) * 4);
  int* srcsP   = (int*)alloc((size_t)(EC + EW) * 4);
  int* rowptrA = (int*)alloc((size_t)(NA + 1) * 4);
  int* degA    = (int*)alloc((size_t)NA * 4);
  int* eidsA   = (int*)alloc((size_t)EB * 4);
  int* srcsA   = (int*)alloc((size_t)EB * 4);
  int* bsumP   = (int*)alloc(64 * 4);
  int* bsumA   = (int*)alloc(64 * 4);
  if (off > ws_size) return;

  const float scale = 0.08838834764831845f;  // 1/sqrt(128)
  const int nbP = (NP + 1023) / 1024, nbA = (NA + 1023) / 1024;

  // --- CSR build ---
  hipMemsetAsync(degP, 0, (size_t)NP * 4, stream);
  hipMemsetAsync(degA, 0, (size_t)NA * 4, stream);
  build_hist<<<dim3((EC + 255) / 256), 256, 0, stream>>>(ei_c + EC, EC, degP);
  build_hist<<<dim3((EW + 255) / 256), 256, 0, stream>>>(ei_w + EW, EW, degP);
  build_hist<<<dim3((EB + 255) / 256), 256, 0, stream>>>(ei_b + EB, EB, degA);
  scan_blk<<<dim3(nbP), 256, 0, stream>>>(degP, NP, rowptrP, bsumP);
  scan_bsum<<<dim3(1), 64, 0, stream>>>(bsumP, nbP, rowptrP + NP);
  scan_add<<<dim3(nbP), 256, 0, stream>>>(rowptrP, bsumP, NP);
  scan_blk<<<dim3(nbA), 256, 0, stream>>>(degA, NA, rowptrA, bsumA);
  scan_bsum<<<dim3(1), 64, 0, stream>>>(bsumA, nbA, rowptrA + NA);
  scan_add<<<dim3(nbA), 256, 0, stream>>>(rowptrA, bsumA, NA);
  hipMemsetAsync(degP, 0, (size_t)NP * 4, stream);
  hipMemsetAsync(degA, 0, (size_t)NA * 4, stream);
  build_scatter<<<dim3((EC + 255) / 256), 256, 0, stream>>>(ei_c, EC, 0, 0,
      rowptrP, degP, eidsP, srcsP);
  build_scatter<<<dim3((EW + 255) / 256), 256, 0, stream>>>(ei_w, EW, EC, 0x40000000,
      rowptrP, degP, eidsP, srcsP);
  build_scatter<<<dim3((EB + 255) / 256), 256, 0, stream>>>(ei_b, EB, 0, 0,
      rowptrA, degA, eidsA, srcsA);

  // --- fused relation weights ---
  FuseArgs fa;
  TrArgs ta;
  for (int l = 0; l < NLAY; l++)
    for (int r = 0; r < 3; r++)
      for (int s = 0; s < 2; s++) {
        int c = (l * 3 + r) * 2 + s;
        int t = (r == 1) ? 1 : 0;
        fa.W[c]   = (s == 0 ? Wk : Wv) + (size_t)(l * 2 + t) * HH;
        fa.rel[c] = (s == 0 ? a_rel : m_rel) + (size_t)(l * 3 + r) * NHEAD * DH * DH;
        fa.bin[c] = (s == 0 ? bk : bv) + (size_t)(l * 2 + t) * HID;
        fa.out[c]  = Wf32 + (size_t)c * HH;
        fa.bout[c] = bff + (size_t)c * HID;
        ta.src[c] = fa.out[c];
        ta.dst[c] = WfT + (size_t)c * HH;
      }
  for (int i = 0; i < 4; i++) {
    ta.src[12 + i] = Wq + (size_t)i * HH;  ta.dst[12 + i] = WqT + (size_t)i * HH;
    ta.src[16 + i] = Wa + (size_t)i * HH;  ta.dst[16 + i] = WaT + (size_t)i * HH;
  }
  gemm_fuse<<<dim3(8, 2, 48), 256, 0, stream>>>(fa);
  transpose20<<<dim3(16, 16, 20), dim3(32, 8), 0, stream>>>(ta);
  bias_fuse_all<<<dim3(12), 512, 0, stream>>>(fa);
  {
    dim3 b(32, 8);
    transpose_to_bf16<<<dim3(8, 16), b, 0, stream>>>(W256, W256T, HID, 256);
    transpose_to_bf16<<<dim3(4, 8), b, 0, stream>>>(W128, W128T, 256, 128);
    transpose_to_bf16<<<dim3(16, 24), b, 0, stream>>>(Wp_paper, WpTp, INDIM, HID);
    transpose_to_bf16<<<dim3(16, 24), b, 0, stream>>>(Wp_author, WpTa, INDIM, HID);
  }

  // --- input conversion + projection ---
  bf16* xb_p = (bf16*)big_p;
  bf16* xb_a = (bf16*)big_a;
  long long nxp = (long long)NP * INDIM, nxa = (long long)NA * INDIM;
  f32_to_bf16<<<dim3((int)((nxp / 4 + 255) / 256)), 256, 0, stream>>>(x_paper, xb_p, nxp);
  f32_to_bf16<<<dim3((int)((nxa / 4 + 255) / 256)), 256, 0, stream>>>(x_author, xb_a, nxa);
  mgemm<bf16>(xb_p, INDIM, WpTp, INDIM, bp_paper, hb_p, HID, NP, HID, INDIM, 0, stream);
  mgemm<bf16>(xb_a, INDIM, WpTa, INDIM, bp_author, hb_a, HID, NA, HID, INDIM, 0, stream);

  for (int l = 0; l < NLAY; l++) {
    const float* prl = p_rel + (size_t)l * 3 * NHEAD;
    int c0K = (l * 3 + 0) * 2, c0V = c0K + 1;
    int c1K = (l * 3 + 1) * 2, c1V = c1K + 1;
    int c2K = (l * 3 + 2) * 2, c2V = c2K + 1;
    // Q
    mgemm<bf16>(hb_p, HID, WqT + (size_t)(l * 2 + 0) * HH, HID, bq + (size_t)(l * 2 + 0) * HID,
                q_p, HID, NP, HID, HID, 0, stream);
    mgemm<bf16>(hb_a, HID, WqT + (size_t)(l * 2 + 1) * HH, HID, bq + (size_t)(l * 2 + 1) * HID,
                q_a, HID, NA, HID, HID, 0, stream);
    // rel0 (cites p->p): kr, alpha
    mgemm<bf16>(hb_p, HID, WfT + (size_t)c0K * HH, HID, bff + (size_t)c0K * HID,
                krv_p, HID, NP, HID, HID, 0, stream);
    edge_alpha<<<dim3((EC + 3) / 4), 256, 0, stream>>>(ei_c, EC, q_p, krv_p, prl + 0, scale, alphaP);
    // rel1 (writes a->p): kr, alpha
    mgemm<bf16>(hb_a, HID, WfT + (size_t)c1K * HH, HID, bff + (size_t)c1K * HID,
                krv_a, HID, NA, HID, HID, 0, stream);
    edge_alpha<<<dim3((EW + 3) / 4), 256, 0, stream>>>(ei_w, EW, q_p, krv_a, prl + NHEAD, scale,
                                                       alphaP + (size_t)EC * NHEAD);
    // vr0/vr1, then fused softmax+agg+gelu -> bf16 into q_p (free now)
    mgemm<bf16>(hb_p, HID, WfT + (size_t)c0V * HH, HID, bff + (size_t)c0V * HID,
                krv_p, HID, NP, HID, HID, 0, stream);
    mgemm<bf16>(hb_a, HID, WfT + (size_t)c1V * HH, HID, bff + (size_t)c1V * HID,
                krv_a, HID, NA, HID, HID, 0, stream);
    csr_softmax_agg<<<dim3((NP + 3) / 4), 256, 0, stream>>>(
        rowptrP, eidsP, srcsP, NP, alphaP, krv_p, krv_a, q_p);
    // rel2 (written_by p->a): kr, alpha, vr, agg+gelu -> q_a
    mgemm<bf16>(hb_p, HID, WfT + (size_t)c2K * HH, HID, bff + (size_t)c2K * HID,
                krv_p, HID, NP, HID, HID, 0, stream);
    edge_alpha<<<dim3((EB + 3) / 4), 256, 0, stream>>>(ei_b, EB, q_a, krv_p, prl + 2 * NHEAD, scale, alphaA);
    mgemm<bf16>(hb_p, HID, WfT + (size_t)c2V * HH, HID, bff + (size_t)c2V * HID,
                krv_p, HID, NP, HID, HID, 0, stream);
    csr_softmax_agg<<<dim3((NA + 3) / 4), 256, 0, stream>>>(
        rowptrA, eidsA, srcsA, NA, alphaA, krv_p, krv_p, q_a);
    // output linear (fp32 out)
    mgemm<float>(q_p, HID, WaT + (size_t)(l * 2 + 0) * HH, HID, ba + (size_t)(l * 2 + 0) * HID,
                 big_p, HID, NP, HID, HID, 0, stream);
    mgemm<float>(q_a, HID, WaT + (size_t)(l * 2 + 1) * HH, HID, ba + (size_t)(l * 2 + 1) * HID,
                 big_a, HID, NA, HID, HID, 0, stream);
    // skip + residual + LN + relu (bf16 h in/out, fp32 math)
    skip_ln_relu_bf<<<dim3(NP), 256, 0, stream>>>(big_p, hb_p, skip + (l * 2 + 0),
                                                  ln_g + (size_t)l * HID, ln_b + (size_t)l * HID, NP);
    skip_ln_relu_bf<<<dim3(NA), 256, 0, stream>>>(big_a, hb_a, skip + (l * 2 + 1),
                                                  ln_g + (size_t)l * HID, ln_b + (size_t)l * HID, NA);
  }

  // final MLP
  mgemm<bf16>(hb_p, HID, W256T, HID, b256, q_p, 256, NP, 256, HID, 1, stream);
  mgemm<float>(q_p, 256, W128T, 256, b128, out, 128, NP, 128, 256, 0, stream);
  mgemm<bf16>(hb_a, HID, W256T, HID, b256, q_a, 256, NA, 256, HID, 1, stream);
  mgemm<float>(q_a, 256, W128T, 256, b128, out + (size_t)NP * 128, 128, NA, 128, 256, 0, stream);
}

// Round 6
// 1316.771 us; speedup vs baseline: 10.7503x; 1.0955x over previous
//
#include <hip/hip_runtime.h>
#include <hip/hip_bf16.h>
#include <math.h>

#define NHEAD 4
#define DH 128
#define HID 512
#define NLAY 2
#define NP 30000
#define NA 10000
#define INDIM 768
#define EC 150000
#define EW 80000
#define EB 80000

typedef __hip_bfloat16 bf16;
typedef __attribute__((ext_vector_type(8))) short bf16x8;
typedef __attribute__((ext_vector_type(4))) float f32x4;

__device__ __forceinline__ void stf(float* p, float v){ *p = v; }
__device__ __forceinline__ void stf(bf16* p, float v){ *p = __float2bfloat16(v); }
__device__ __forceinline__ unsigned short f2bu(float f){ bf16 t = __float2bfloat16(f); return *(unsigned short*)&t; }
__device__ __forceinline__ float bu2f(unsigned short u){ return __uint_as_float((unsigned)u << 16); }

__device__ __forceinline__ void load8b(const bf16* __restrict__ p, int i8, float* o){
  uint4 r = ((const uint4*)p)[i8];
  o[0]=__uint_as_float(r.x<<16); o[1]=__uint_as_float(r.x&0xffff0000u);
  o[2]=__uint_as_float(r.y<<16); o[3]=__uint_as_float(r.y&0xffff0000u);
  o[4]=__uint_as_float(r.z<<16); o[5]=__uint_as_float(r.z&0xffff0000u);
  o[6]=__uint_as_float(r.w<<16); o[7]=__uint_as_float(r.w&0xffff0000u);
}

// async global->LDS, 16B per lane, wave-uniform LDS base + lane*16 (HW semantics)
__device__ __forceinline__ void gload16(const void* g, void* l) {
  __builtin_amdgcn_global_load_lds((const __attribute__((address_space(1))) void*)g,
                                   (__attribute__((address_space(3))) void*)l, 16, 0, 0);
}

// ---------------------------------------------------------------------------
// MFMA bf16 GEMM: C[M,N] = A[M,K] @ Bt[N,K]^T (+bias fp32) (+relu)
// 128x128 tile, BK=64, 4 waves x (4x4) frags of 16x16x32.
// 1D grid, bn-fastest + chunked bijective XCD swizzle (m204) -> blocks
// sharing an A row-panel land on one XCD's L2.
// 2-phase double-buffered prefetch: STAGE(next) issued before compute(cur),
// one __syncthreads (vmcnt drain) per K-step.
// Staging via global_load_lds 16B with pre-swizzled GLOBAL source
// (kc ^= row&7), linear LDS dest; ds_read applies matching swizzle.
// Requires N%128==0, K%64==0. M guarded.
// ---------------------------------------------------------------------------
template<typename TC>
__global__ __launch_bounds__(256)
void mfma_gemm(const bf16* __restrict__ A, int lda,
               const bf16* __restrict__ Bt, int ldb,
               const float* __restrict__ bias,
               TC* __restrict__ C, int ldc,
               int M, int N, int K, int act, int nbn)
{
  __shared__ __align__(16) short As[2][128 * 64];
  __shared__ __align__(16) short Bs[2][128 * 64];
  const int tid = threadIdx.x;
  const int lane = tid & 63, w = tid >> 6;
  // chunked bijective XCD swizzle (m204): consecutive work -> same XCD
  const int nwg = gridDim.x;
  const int bid = blockIdx.x;
  const int xcd = bid & 7, pos = bid >> 3;
  const int q8 = nwg >> 3, r8 = nwg & 7;
  const int work = (xcd < r8 ? xcd * (q8 + 1) : r8 * (q8 + 1) + (xcd - r8) * q8) + pos;
  const int brow = (work / nbn) * 128, bcol = (work % nbn) * 128;
  const int wr = w >> 1, wc = w & 1;

  f32x4 acc[4][4];
#pragma unroll
  for (int m = 0; m < 4; m++)
#pragma unroll
    for (int n = 0; n < 4; n++) acc[m][n] = (f32x4){0.f, 0.f, 0.f, 0.f};

  auto STAGE = [&](int buf, int k0) {
#pragma unroll
    for (int i = 0; i < 4; i++) {
      int chunk = i * 4 + w;                   // wave-uniform
      int c_lin = chunk * 64 + lane;           // 16B-chunk index in tile
      int row = c_lin >> 3;
      int kc = ((c_lin & 7) ^ (row & 7)) * 8;  // inverse-swizzled source k
      int growA = brow + row; growA = growA < M ? growA : M - 1;
      gload16(A + (size_t)growA * lda + k0 + kc, &As[buf][chunk * 512]);
      gload16(Bt + (size_t)(bcol + row) * ldb + k0 + kc, &Bs[buf][chunk * 512]);
    }
  };

  const int nk = K >> 6;
  STAGE(0, 0);
  __syncthreads();          // drain prefetch (vmcnt0) + barrier
  int buf = 0;
  for (int t = 0; t < nk; t++) {
    if (t + 1 < nk) STAGE(buf ^ 1, (t + 1) << 6);   // async prefetch
#pragma unroll
    for (int kk = 0; kk < 2; kk++) {
      const int ke = kk * 32 + (lane >> 4) * 8;
      bf16x8 af[4], bq[4];
#pragma unroll
      for (int m = 0; m < 4; m++) {
        int row = wr * 64 + m * 16 + (lane & 15);
        af[m] = *(const bf16x8*)(&As[buf][row * 64 + (ke ^ ((row & 7) << 3))]);
      }
#pragma unroll
      for (int n = 0; n < 4; n++) {
        int col = wc * 64 + n * 16 + (lane & 15);
        bq[n] = *(const bf16x8*)(&Bs[buf][col * 64 + (ke ^ ((col & 7) << 3))]);
      }
#pragma unroll
      for (int m = 0; m < 4; m++)
#pragma unroll
        for (int n = 0; n < 4; n++)
          acc[m][n] = __builtin_amdgcn_mfma_f32_16x16x32_bf16(af[m], bq[n], acc[m][n], 0, 0, 0);
    }
    __syncthreads();        // all waves done reading buf; prefetch landed
    buf ^= 1;
  }

#pragma unroll
  for (int m = 0; m < 4; m++) {
    int gr0 = brow + wr * 64 + m * 16 + (lane >> 4) * 4;
#pragma unroll
    for (int n = 0; n < 4; n++) {
      int gc = bcol + wc * 64 + n * 16 + (lane & 15);
      float bv = bias ? bias[gc] : 0.f;
#pragma unroll
      for (int r = 0; r < 4; r++) {
        int gr = gr0 + r;
        if (gr < M) {
          float v = acc[m][n][r] + bv;
          if (act) v = fmaxf(v, 0.f);
          stf(&C[(size_t)gr * ldc + gc], v);
        }
      }
    }
  }
}

// ---------------------------------------------------------------------------
// Weight preparation
// ---------------------------------------------------------------------------
struct FuseArgs {
  const float* W[12];
  const float* rel[12];
  const float* bin[12];
  float* out[12];
  float* bout[12];
};
struct TrArgs {            // 20x [512,512] fp32 -> bf16 transposed
  const float* src[20];
  bf16* dst[20];
};

__global__ __launch_bounds__(256)
void gemm_fuse(FuseArgs fa)
{
  int c = blockIdx.z >> 2, h = blockIdx.z & 3;
  const float* A = fa.W[c] + h * 128;
  const float* B = fa.rel[c] + (size_t)h * 128 * 128;
  float* C = fa.out[c] + h * 128;
  __shared__ float Ast[64][17];
  __shared__ float Bst[16][64];
  const int tid = threadIdx.x;
  const int tx = tid & 15, ty = tid >> 4;
  const int bm = blockIdx.x * 64, bn = blockIdx.y * 64;
  float acc[4][4] = {};
  for (int k0 = 0; k0 < 128; k0 += 16) {
#pragma unroll
    for (int i = 0; i < 4; i++) {
      int lin = tid + i * 256;
      int m = lin >> 4, kk = lin & 15;
      Ast[m][kk] = A[(size_t)(bm + m) * 512 + k0 + kk];
      int kb = lin >> 6, nb = lin & 63;
      Bst[kb][nb] = B[(size_t)(k0 + kb) * 128 + bn + nb];
    }
    __syncthreads();
#pragma unroll
    for (int kk = 0; kk < 16; kk++) {
      float a[4], b[4];
#pragma unroll
      for (int i = 0; i < 4; i++) a[i] = Ast[ty * 4 + i][kk];
#pragma unroll
      for (int j = 0; j < 4; j++) b[j] = Bst[kk][tx * 4 + j];
#pragma unroll
      for (int i = 0; i < 4; i++)
#pragma unroll
        for (int j = 0; j < 4; j++)
          acc[i][j] = fmaf(a[i], b[j], acc[i][j]);
    }
    __syncthreads();
  }
#pragma unroll
  for (int i = 0; i < 4; i++)
#pragma unroll
    for (int j = 0; j < 4; j++)
      C[(size_t)(bm + ty * 4 + i) * 512 + bn + tx * 4 + j] = acc[i][j];
}

__global__ __launch_bounds__(256)
void transpose20(TrArgs ta)
{
  int c = blockIdx.z;
  const float* in = ta.src[c];
  bf16* o = ta.dst[c];
  __shared__ float t[32][33];
  int bn = blockIdx.x * 32, bk = blockIdx.y * 32;
  int x = threadIdx.x, y = threadIdx.y;
#pragma unroll
  for (int i = 0; i < 32; i += 8)
    t[y + i][x] = in[(size_t)(bk + y + i) * 512 + bn + x];
  __syncthreads();
#pragma unroll
  for (int i = 0; i < 32; i += 8)
    o[(size_t)(bn + y + i) * 512 + bk + x] = __float2bfloat16(t[x][y + i]);
}

__global__ __launch_bounds__(512)
void bias_fuse_all(FuseArgs fa)
{
  int c = blockIdx.x;
  int j = threadIdx.x;
  int h = j >> 7, e = j & 127;
  const float* bh = fa.bin[c] + h * DH;
  const float* rh = fa.rel[c] + (size_t)h * DH * DH;
  float s = 0.f;
  for (int d = 0; d < DH; d++) s = fmaf(bh[d], rh[d * DH + e], s);
  fa.bout[c][j] = s;
}

__global__ __launch_bounds__(256)
void transpose_to_bf16(const float* __restrict__ in, bf16* __restrict__ out,
                       int K_, int N_)
{
  __shared__ float t[32][33];
  int bn = blockIdx.x * 32, bk = blockIdx.y * 32;
  int x = threadIdx.x, y = threadIdx.y;
#pragma unroll
  for (int i = 0; i < 32; i += 8) {
    int k = bk + y + i, n = bn + x;
    if (k < K_ && n < N_) t[y + i][x] = in[(size_t)k * N_ + n];
  }
  __syncthreads();
#pragma unroll
  for (int i = 0; i < 32; i += 8) {
    int n = bn + y + i, k = bk + x;
    if (n < N_ && k < K_) out[(size_t)n * K_ + k] = __float2bfloat16(t[x][y + i]);
  }
}

__global__ __launch_bounds__(256)
void f32_to_bf16(const float* __restrict__ x, bf16* __restrict__ y, long long n)
{
  long long i = ((long long)blockIdx.x * 256 + threadIdx.x) * 4;
  if (i >= n) return;
  float4 v = *(const float4*)(x + i);
  ushort4 o;
  o.x = f2bu(v.x); o.y = f2bu(v.y); o.z = f2bu(v.z); o.w = f2bu(v.w);
  *(ushort4*)(y + i) = o;
}

// ---------------------------------------------------------------------------
// Edge / attention kernels (kr/vr live in [*,1024] kv slabs -> ld param)
// ---------------------------------------------------------------------------
__global__ __launch_bounds__(256)
void edge_alpha(const int* __restrict__ ei, int E,
                const bf16* __restrict__ q, const bf16* __restrict__ kr, int ldk,
                const float* __restrict__ p_rel, float scale,
                float* __restrict__ alpha)
{
  int edge = blockIdx.x * 4 + (threadIdx.x >> 6);
  int lane = threadIdx.x & 63;
  if (edge >= E) return;
  int src = ei[edge];
  int dst = ei[E + edge];
  float qv[8], kv[8];
  load8b(q + (size_t)dst * HID, lane, qv);
  load8b(kr + (size_t)src * ldk, lane, kv);
  float s = 0.f;
#pragma unroll
  for (int i = 0; i < 8; i++) s = fmaf(qv[i], kv[i], s);
  s += __shfl_xor(s, 8);
  s += __shfl_xor(s, 4);
  s += __shfl_xor(s, 2);
  s += __shfl_xor(s, 1);
  int h = lane >> 4;
  if ((lane & 15) == 0) alpha[(size_t)edge * NHEAD + h] = s * p_rel[h] * scale;
}

__global__ __launch_bounds__(256)
void build_hist(const int* __restrict__ ei_dst, int E, int* __restrict__ deg)
{
  int i = blockIdx.x * 256 + threadIdx.x;
  if (i < E) atomicAdd(&deg[ei_dst[i]], 1);
}

// --------- hierarchical exclusive scan (3 phases) ---------
__global__ __launch_bounds__(256)
void scan_blk(const int* __restrict__ deg, int n, int* __restrict__ rowptr,
              int* __restrict__ bsum)
{
  __shared__ int sh[256];
  int t = threadIdx.x;
  int base = blockIdx.x * 1024 + t * 4;
  int v0 = 0, v1 = 0, v2 = 0, v3 = 0;
  if (base + 3 < n) {
    int4 v = *(const int4*)(deg + base);
    v0 = v.x; v1 = v.y; v2 = v.z; v3 = v.w;
  } else {
    if (base < n)     v0 = deg[base];
    if (base + 1 < n) v1 = deg[base + 1];
    if (base + 2 < n) v2 = deg[base + 2];
    if (base + 3 < n) v3 = deg[base + 3];
  }
  int s = v0 + v1 + v2 + v3;
  sh[t] = s;
  __syncthreads();
#pragma unroll
  for (int off = 1; off < 256; off <<= 1) {
    int tv = (t >= off) ? sh[t - off] : 0;
    __syncthreads();
    sh[t] += tv;
    __syncthreads();
  }
  int excl = sh[t] - s;
  if (t == 255) bsum[blockIdx.x] = sh[255];
  if (base < n)     rowptr[base] = excl;
  if (base + 1 < n) rowptr[base + 1] = excl + v0;
  if (base + 2 < n) rowptr[base + 2] = excl + v0 + v1;
  if (base + 3 < n) rowptr[base + 3] = excl + v0 + v1 + v2;
}

__global__ __launch_bounds__(64)
void scan_bsum(int* __restrict__ bsum, int nb, int* __restrict__ rowptr_end)
{
  int t = threadIdx.x;
  int v = (t < nb) ? bsum[t] : 0;
  int inc = v;
#pragma unroll
  for (int off = 1; off < 64; off <<= 1) {
    int o = __shfl_up(inc, off);
    if (t >= off) inc += o;
  }
  if (t < nb) bsum[t] = inc - v;
  if (t == nb - 1) *rowptr_end = inc;
}

__global__ __launch_bounds__(256)
void scan_add(int* __restrict__ rowptr, const int* __restrict__ bsum, int n)
{
  int add = bsum[blockIdx.x];
  if (add == 0) return;
  int i = blockIdx.x * 1024 + threadIdx.x * 4;
  if (i < n)     rowptr[i] += add;
  if (i + 1 < n) rowptr[i + 1] += add;
  if (i + 2 < n) rowptr[i + 2] += add;
  if (i + 3 < n) rowptr[i + 3] += add;
}

__global__ __launch_bounds__(256)
void build_scatter(const int* __restrict__ ei, int E, int eid_base, int flag,
                   const int* __restrict__ rowptr, int* __restrict__ cursor,
                   int* __restrict__ eids, int* __restrict__ srcs)
{
  int e = blockIdx.x * 256 + threadIdx.x;
  if (e >= E) return;
  int src = ei[e];
  int dst = ei[E + e];
  int pos = rowptr[dst] + atomicAdd(&cursor[dst], 1);
  eids[pos] = eid_base + e;
  srcs[pos] = src | flag;
}

// fused segment softmax + aggregate + exact gelu -> bf16 output row
__global__ __launch_bounds__(256)
void csr_softmax_agg(const int* __restrict__ rowptr, const int* __restrict__ eids,
                     const int* __restrict__ srcs, int nnode,
                     const float* __restrict__ alpha,
                     const bf16* __restrict__ vr0, const bf16* __restrict__ vr1,
                     int ldv, bf16* __restrict__ outb)
{
  int node = blockIdx.x * 4 + (threadIdx.x >> 6);
  if (node >= nnode) return;
  int lane = threadIdx.x & 63;
  int h = lane >> 4, j = lane & 15;
  int beg = rowptr[node], end = rowptr[node + 1];
  float mx = -INFINITY;
  for (int p = beg + j; p < end; p += 16)
    mx = fmaxf(mx, alpha[(size_t)eids[p] * NHEAD + h]);
  mx = fmaxf(mx, __shfl_xor(mx, 1));
  mx = fmaxf(mx, __shfl_xor(mx, 2));
  mx = fmaxf(mx, __shfl_xor(mx, 4));
  mx = fmaxf(mx, __shfl_xor(mx, 8));
  if (!isfinite(mx)) mx = 0.f;
  float sm = 0.f;
  for (int p = beg + j; p < end; p += 16)
    sm += expf(alpha[(size_t)eids[p] * NHEAD + h] - mx);
  sm += __shfl_xor(sm, 1);
  sm += __shfl_xor(sm, 2);
  sm += __shfl_xor(sm, 4);
  sm += __shfl_xor(sm, 8);
  float inv = 1.f / (sm + 1e-16f);
  float acc[8] = {};
  for (int p = beg; p < end; ++p) {
    int se = srcs[p];
    int src = se & 0x3FFFFFFF;
    const bf16* table = (se & 0x40000000) ? vr1 : vr0;
    float wgt = expf(alpha[(size_t)eids[p] * NHEAD + h] - mx) * inv;
    float v[8];
    load8b(table + (size_t)src * ldv, lane, v);
#pragma unroll
    for (int i = 0; i < 8; i++) acc[i] = fmaf(wgt, v[i], acc[i]);
  }
  unsigned short g[8];
#pragma unroll
  for (int i = 0; i < 8; i++)
    g[i] = f2bu(0.5f * acc[i] * (1.f + erff(acc[i] * 0.70710678118654752f)));
  uint4 o;
  o.x = g[0] | ((unsigned)g[1] << 16);
  o.y = g[2] | ((unsigned)g[3] << 16);
  o.z = g[4] | ((unsigned)g[5] << 16);
  o.w = g[6] | ((unsigned)g[7] << 16);
  *(uint4*)(outb + (size_t)node * HID + lane * 8) = o;
}

// h[row,:] = relu(LN(sp*oplin + (2-sp)*h)) ; oplin fp32, h bf16 in/out
__global__ __launch_bounds__(256)
void skip_ln_relu_bf(const float* __restrict__ oplin, bf16* __restrict__ h,
                     const float* __restrict__ skipv,
                     const float* __restrict__ g, const float* __restrict__ b,
                     int rows)
{
  int row = blockIdx.x;
  if (row >= rows) return;
  float sp = 1.f / (1.f + expf(-skipv[0]));
  const float2* o2 = (const float2*)(oplin + (size_t)row * HID);
  ushort2* h2 = (ushort2*)(h + (size_t)row * HID);
  int t = threadIdx.x;
  float2 ov = o2[t];
  ushort2 hv = h2[t];
  float t0 = sp * ov.x + (2.f - sp) * bu2f(hv.x);
  float t1 = sp * ov.y + (2.f - sp) * bu2f(hv.y);
  float s = t0 + t1, ss = t0 * t0 + t1 * t1;
#pragma unroll
  for (int off = 32; off; off >>= 1) {
    s += __shfl_down(s, off);
    ss += __shfl_down(ss, off);
  }
  __shared__ float sh[8];
  int wid = t >> 6, lane = t & 63;
  if (lane == 0) { sh[wid] = s; sh[4 + wid] = ss; }
  __syncthreads();
  if (t == 0) {
    float S = 0, SS = 0;
    for (int wv = 0; wv < 4; wv++) { S += sh[wv]; SS += sh[4 + wv]; }
    sh[0] = S; sh[4] = SS;
  }
  __syncthreads();
  float mu = sh[0] * (1.f / 512.f);
  float var = sh[4] * (1.f / 512.f) - mu * mu;
  float inv = rsqrtf(var + 1e-5f);
  float y0 = (t0 - mu) * inv * g[2 * t] + b[2 * t];
  float y1 = (t1 - mu) * inv * g[2 * t + 1] + b[2 * t + 1];
  ushort2 o;
  o.x = f2bu(fmaxf(y0, 0.f));
  o.y = f2bu(fmaxf(y1, 0.f));
  h2[t] = o;
}

// ---------------------------------------------------------------------------
template<typename TC>
static inline void mgemm(const bf16* A, int lda, const bf16* Bt, int ldb,
                         const float* bias, TC* C, int ldc,
                         int M, int N, int K, int act, hipStream_t s)
{
  int nbm = (M + 127) / 128, nbn = N / 128;
  dim3 grid(nbm * nbn), block(256);
  mfma_gemm<TC><<<grid, block, 0, s>>>(A, lda, Bt, ldb, bias, C, ldc, M, N, K, act, nbn);
}

extern "C" void kernel_launch(void* const* d_in, const int* in_sizes, int n_in,
                              void* d_out, int out_size, void* d_ws, size_t ws_size,
                              hipStream_t stream)
{
  const float* x_paper  = (const float*)d_in[0];
  const float* x_author = (const float*)d_in[1];
  const float* Wp_paper = (const float*)d_in[2];
  const float* bp_paper = (const float*)d_in[3];
  const float* Wp_author= (const float*)d_in[4];
  const float* bp_author= (const float*)d_in[5];
  const float* Wk = (const float*)d_in[6];
  const float* bk = (const float*)d_in[7];
  const float* Wq = (const float*)d_in[8];
  const float* bq = (const float*)d_in[9];
  const float* Wv = (const float*)d_in[10];
  const float* bv = (const float*)d_in[11];
  const float* Wa = (const float*)d_in[12];
  const float* ba = (const float*)d_in[13];
  const float* skip = (const float*)d_in[14];
  const float* a_rel = (const float*)d_in[15];
  const float* m_rel = (const float*)d_in[16];
  const float* p_rel = (const float*)d_in[17];
  const float* ln_g = (const float*)d_in[18];
  const float* ln_b = (const float*)d_in[19];
  const float* W256 = (const float*)d_in[20];
  const float* b256 = (const float*)d_in[21];
  const float* W128 = (const float*)d_in[22];
  const float* b128 = (const float*)d_in[23];
  const int* ei_c = (const int*)d_in[24];
  const int* ei_w = (const int*)d_in[25];
  const int* ei_b = (const int*)d_in[26];
  float* out = (float*)d_out;

  const size_t NPe = (size_t)NP * HID, NAe = (size_t)NA * HID;
  const size_t HH = (size_t)HID * HID;
  char* w = (char*)d_ws;
  size_t off = 0;
  auto alloc = [&](size_t bytes) -> void* {
    void* p = (void*)(w + off);
    off += (bytes + 255) & ~(size_t)255;
    return p;
  };
  bf16* hb_p  = (bf16*)alloc(NPe * 2);
  bf16* hb_a  = (bf16*)alloc(NAe * 2);
  bf16* q_p   = (bf16*)alloc(NPe * 2);   // q -> gelu(op) -> h256
  bf16* q_a   = (bf16*)alloc(NAe * 2);
  float* big_p = (float*)alloc(NPe * 4); // xb_p -> kv_p [NP,1024]bf16 -> oplin f32
  float* big_a = (float*)alloc(NAe * 4); // xb_a -> kv_a [NA,1024]bf16 -> oplin f32
  float* Wf32 = (float*)alloc(12 * HH * 4);
  bf16* WfT   = (bf16*)alloc(12 * HH * 2);   // 6 pairs x [1024,512]
  float* bff  = (float*)alloc(6 * 1024 * 4); // 6 pairs x [1024] (K|V)
  bf16* WqT   = (bf16*)alloc(4 * HH * 2);
  bf16* WaT   = (bf16*)alloc(4 * HH * 2);
  bf16* W256T = (bf16*)alloc((size_t)HID * 256 * 2);
  bf16* W128T = (bf16*)alloc((size_t)256 * 128 * 2);
  bf16* WpTp  = (bf16*)alloc((size_t)INDIM * HID * 2);
  bf16* WpTa  = (bf16*)alloc((size_t)INDIM * HID * 2);
  float* alphaP = (float*)alloc((size_t)(EC + EW) * NHEAD * 4);
  float* alphaA = (float*)alloc((size_t)EB * NHEAD * 4);
  int* rowptrP = (int*)alloc((size_t)(NP + 1) * 4);
  int* degP    = (int*)alloc((size_t)NP * 4);
  int* eidsP   = (int*)alloc((size_t)(EC + EW) * 4);
  int* srcsP   = (int*)alloc((size_t)(EC + EW) * 4);
  int* rowptrA = (int*)alloc((size_t)(NA + 1) * 4);
  int* degA    = (int*)alloc((size_t)NA * 4);
  int* eidsA   = (int*)alloc((size_t)EB * 4);
  int* srcsA   = (int*)alloc((size_t)EB * 4);
  int* bsumP   = (int*)alloc(64 * 4);
  int* bsumA   = (int*)alloc(64 * 4);
  if (off > ws_size) return;

  const float scale = 0.08838834764831845f;  // 1/sqrt(128)
  const int nbP = (NP + 1023) / 1024, nbA = (NA + 1023) / 1024;

  // --- CSR build ---
  hipMemsetAsync(degP, 0, (size_t)NP * 4, stream);
  hipMemsetAsync(degA, 0, (size_t)NA * 4, stream);
  build_hist<<<dim3((EC + 255) / 256), 256, 0, stream>>>(ei_c + EC, EC, degP);
  build_hist<<<dim3((EW + 255) / 256), 256, 0, stream>>>(ei_w + EW, EW, degP);
  build_hist<<<dim3((EB + 255) / 256), 256, 0, stream>>>(ei_b + EB, EB, degA);
  scan_blk<<<dim3(nbP), 256, 0, stream>>>(degP, NP, rowptrP, bsumP);
  scan_bsum<<<dim3(1), 64, 0, stream>>>(bsumP, nbP, rowptrP + NP);
  scan_add<<<dim3(nbP), 256, 0, stream>>>(rowptrP, bsumP, NP);
  scan_blk<<<dim3(nbA), 256, 0, stream>>>(degA, NA, rowptrA, bsumA);
  scan_bsum<<<dim3(1), 64, 0, stream>>>(bsumA, nbA, rowptrA + NA);
  scan_add<<<dim3(nbA), 256, 0, stream>>>(rowptrA, bsumA, NA);
  hipMemsetAsync(degP, 0, (size_t)NP * 4, stream);
  hipMemsetAsync(degA, 0, (size_t)NA * 4, stream);
  build_scatter<<<dim3((EC + 255) / 256), 256, 0, stream>>>(ei_c, EC, 0, 0,
      rowptrP, degP, eidsP, srcsP);
  build_scatter<<<dim3((EW + 255) / 256), 256, 0, stream>>>(ei_w, EW, EC, 0x40000000,
      rowptrP, degP, eidsP, srcsP);
  build_scatter<<<dim3((EB + 255) / 256), 256, 0, stream>>>(ei_b, EB, 0, 0,
      rowptrA, degA, eidsA, srcsA);

  // --- fused relation weights; WfT pairs [kr rows | vr rows], bff pairs ---
  FuseArgs fa;
  TrArgs ta;
  for (int l = 0; l < NLAY; l++)
    for (int r = 0; r < 3; r++)
      for (int s = 0; s < 2; s++) {
        int c = (l * 3 + r) * 2 + s;
        int pair = l * 3 + r;
        int t = (r == 1) ? 1 : 0;
        fa.W[c]   = (s == 0 ? Wk : Wv) + (size_t)(l * 2 + t) * HH;
        fa.rel[c] = (s == 0 ? a_rel : m_rel) + (size_t)(l * 3 + r) * NHEAD * DH * DH;
        fa.bin[c] = (s == 0 ? bk : bv) + (size_t)(l * 2 + t) * HID;
        fa.out[c]  = Wf32 + (size_t)c * HH;
        fa.bout[c] = bff + (size_t)pair * 1024 + s * 512;
        ta.src[c] = fa.out[c];
        ta.dst[c] = WfT + (size_t)pair * 2 * HH + (size_t)s * HH;  // [1024,512]
      }
  for (int i = 0; i < 4; i++) {
    ta.src[12 + i] = Wq + (size_t)i * HH;  ta.dst[12 + i] = WqT + (size_t)i * HH;
    ta.src[16 + i] = Wa + (size_t)i * HH;  ta.dst[16 + i] = WaT + (size_t)i * HH;
  }
  gemm_fuse<<<dim3(8, 2, 48), 256, 0, stream>>>(fa);
  transpose20<<<dim3(16, 16, 20), dim3(32, 8), 0, stream>>>(ta);
  bias_fuse_all<<<dim3(12), 512, 0, stream>>>(fa);
  {
    dim3 b(32, 8);
    transpose_to_bf16<<<dim3(8, 16), b, 0, stream>>>(W256, W256T, HID, 256);
    transpose_to_bf16<<<dim3(4, 8), b, 0, stream>>>(W128, W128T, 256, 128);
    transpose_to_bf16<<<dim3(16, 24), b, 0, stream>>>(Wp_paper, WpTp, INDIM, HID);
    transpose_to_bf16<<<dim3(16, 24), b, 0, stream>>>(Wp_author, WpTa, INDIM, HID);
  }

  // --- input conversion + projection ---
  bf16* xb_p = (bf16*)big_p;
  bf16* xb_a = (bf16*)big_a;
  long long nxp = (long long)NP * INDIM, nxa = (long long)NA * INDIM;
  f32_to_bf16<<<dim3((int)((nxp / 4 + 255) / 256)), 256, 0, stream>>>(x_paper, xb_p, nxp);
  f32_to_bf16<<<dim3((int)((nxa / 4 + 255) / 256)), 256, 0, stream>>>(x_author, xb_a, nxa);
  mgemm<bf16>(xb_p, INDIM, WpTp, INDIM, bp_paper, hb_p, HID, NP, HID, INDIM, 0, stream);
  mgemm<bf16>(xb_a, INDIM, WpTa, INDIM, bp_author, hb_a, HID, NA, HID, INDIM, 0, stream);

  for (int l = 0; l < NLAY; l++) {
    const float* prl = p_rel + (size_t)l * 3 * NHEAD;
    const bf16* WfT0 = WfT + (size_t)(l * 3 + 0) * 2 * HH;
    const bf16* WfT1 = WfT + (size_t)(l * 3 + 1) * 2 * HH;
    const bf16* WfT2 = WfT + (size_t)(l * 3 + 2) * 2 * HH;
    const float* bf0 = bff + (size_t)(l * 3 + 0) * 1024;
    const float* bf1 = bff + (size_t)(l * 3 + 1) * 1024;
    const float* bf2 = bff + (size_t)(l * 3 + 2) * 1024;
    bf16* kv_p = (bf16*)big_p;   // [NP,1024]: kr | vr
    bf16* kv_a = (bf16*)big_a;   // [NA,1024]

    // Q
    mgemm<bf16>(hb_p, HID, WqT + (size_t)(l * 2 + 0) * HH, HID, bq + (size_t)(l * 2 + 0) * HID,
                q_p, HID, NP, HID, HID, 0, stream);
    mgemm<bf16>(hb_a, HID, WqT + (size_t)(l * 2 + 1) * HH, HID, bq + (size_t)(l * 2 + 1) * HID,
                q_a, HID, NA, HID, HID, 0, stream);
    // rel0 (cites p->p): fused kr|vr, alpha
    mgemm<bf16>(hb_p, HID, WfT0, HID, bf0, kv_p, 1024, NP, 1024, HID, 0, stream);
    edge_alpha<<<dim3((EC + 3) / 4), 256, 0, stream>>>(ei_c, EC, q_p, kv_p, 1024,
                                                       prl + 0, scale, alphaP);
    // rel1 (writes a->p): fused kr|vr, alpha
    mgemm<bf16>(hb_a, HID, WfT1, HID, bf1, kv_a, 1024, NA, 1024, HID, 0, stream);
    edge_alpha<<<dim3((EW + 3) / 4), 256, 0, stream>>>(ei_w, EW, q_p, kv_a, 1024,
                                                       prl + NHEAD, scale,
                                                       alphaP + (size_t)EC * NHEAD);
    // paper softmax+agg+gelu -> q_p (dead after paper alphas)
    csr_softmax_agg<<<dim3((NP + 3) / 4), 256, 0, stream>>>(
        rowptrP, eidsP, srcsP, NP, alphaP, kv_p + 512, kv_a + 512, 1024, q_p);
    // rel2 (written_by p->a): fused kr|vr overwrites kv_p, alpha, agg -> q_a
    mgemm<bf16>(hb_p, HID, WfT2, HID, bf2, kv_p, 1024, NP, 1024, HID, 0, stream);
    edge_alpha<<<dim3((EB + 3) / 4), 256, 0, stream>>>(ei_b, EB, q_a, kv_p, 1024,
                                                       prl + 2 * NHEAD, scale, alphaA);
    csr_softmax_agg<<<dim3((NA + 3) / 4), 256, 0, stream>>>(
        rowptrA, eidsA, srcsA, NA, alphaA, kv_p + 512, kv_p + 512, 1024, q_a);
    // output linear (fp32 out into big slabs; kv dead)
    mgemm<float>(q_p, HID, WaT + (size_t)(l * 2 + 0) * HH, HID, ba + (size_t)(l * 2 + 0) * HID,
                 big_p, HID, NP, HID, HID, 0, stream);
    mgemm<float>(q_a, HID, WaT + (size_t)(l * 2 + 1) * HH, HID, ba + (size_t)(l * 2 + 1) * HID,
                 big_a, HID, NA, HID, HID, 0, stream);
    // skip + residual + LN + relu
    skip_ln_relu_bf<<<dim3(NP), 256, 0, stream>>>(big_p, hb_p, skip + (l * 2 + 0),
                                                  ln_g + (size_t)l * HID, ln_b + (size_t)l * HID, NP);
    skip_ln_relu_bf<<<dim3(NA), 256, 0, stream>>>(big_a, hb_a, skip + (l * 2 + 1),
                                                  ln_g + (size_t)l * HID, ln_b + (size_t)l * HID, NA);
  }

  // final MLP
  mgemm<bf16>(hb_p, HID, W256T, HID, b256, q_p, 256, NP, 256, HID, 1, stream);
  mgemm<float>(q_p, 256, W128T, 256, b128, out, 128, NP, 128, 256, 0, stream);
  mgemm<bf16>(hb_a, HID, W256T, HID, b256, q_a, 256, NA, 256, HID, 1, stream);
  mgemm<float>(q_a, 256, W128T, 256, b128, out + (size_t)NP * 128, 128, NA, 128, 256, 0, stream);
}

// Round 7
// 1167.426 us; speedup vs baseline: 12.1256x; 1.1279x over previous
//
#include <hip/hip_runtime.h>
#include <hip/hip_bf16.h>
#include <math.h>

#define NHEAD 4
#define DH 128
#define HID 512
#define NLAY 2
#define NP 30000
#define NA 10000
#define INDIM 768
#define EC 150000
#define EW 80000
#define EB 80000

typedef __hip_bfloat16 bf16;
typedef __attribute__((ext_vector_type(8))) short bf16x8;
typedef __attribute__((ext_vector_type(4))) float f32x4;

__device__ __forceinline__ void stf(float* p, float v){ *p = v; }
__device__ __forceinline__ void stf(bf16* p, float v){ *p = __float2bfloat16(v); }
__device__ __forceinline__ unsigned short f2bu(float f){ bf16 t = __float2bfloat16(f); return *(unsigned short*)&t; }
__device__ __forceinline__ float bu2f(unsigned short u){ return __uint_as_float((unsigned)u << 16); }

__device__ __forceinline__ void load8b(const bf16* __restrict__ p, int i8, float* o){
  uint4 r = ((const uint4*)p)[i8];
  o[0]=__uint_as_float(r.x<<16); o[1]=__uint_as_float(r.x&0xffff0000u);
  o[2]=__uint_as_float(r.y<<16); o[3]=__uint_as_float(r.y&0xffff0000u);
  o[4]=__uint_as_float(r.z<<16); o[5]=__uint_as_float(r.z&0xffff0000u);
  o[6]=__uint_as_float(r.w<<16); o[7]=__uint_as_float(r.w&0xffff0000u);
}

// async global->LDS, 16B per lane, wave-uniform LDS base + lane*16
__device__ __forceinline__ void gload16(const void* g, void* l) {
  __builtin_amdgcn_global_load_lds((const __attribute__((address_space(1))) void*)g,
                                   (__attribute__((address_space(3))) void*)l, 16, 0, 0);
}

// ---------------------------------------------------------------------------
// MFMA bf16 GEMM: C[M,N] = A[M,K] @ Bt[N,K]^T (+bias fp32) (+relu)
// 128x128 tile, BK=64, 2-phase dbuf prefetch, bn-fastest 1D grid with
// chunked bijective XCD swizzle, global_load_lds staging w/ source swizzle.
// ---------------------------------------------------------------------------
template<typename TC>
__global__ __launch_bounds__(256)
void mfma_gemm(const bf16* __restrict__ A, int lda,
               const bf16* __restrict__ Bt, int ldb,
               const float* __restrict__ bias,
               TC* __restrict__ C, int ldc,
               int M, int N, int K, int act, int nbn)
{
  __shared__ __align__(16) short As[2][128 * 64];
  __shared__ __align__(16) short Bs[2][128 * 64];
  const int tid = threadIdx.x;
  const int lane = tid & 63, w = tid >> 6;
  const int nwg = gridDim.x;
  const int bid = blockIdx.x;
  const int xcd = bid & 7, pos = bid >> 3;
  const int q8 = nwg >> 3, r8 = nwg & 7;
  const int work = (xcd < r8 ? xcd * (q8 + 1) : r8 * (q8 + 1) + (xcd - r8) * q8) + pos;
  const int brow = (work / nbn) * 128, bcol = (work % nbn) * 128;
  const int wr = w >> 1, wc = w & 1;

  f32x4 acc[4][4];
#pragma unroll
  for (int m = 0; m < 4; m++)
#pragma unroll
    for (int n = 0; n < 4; n++) acc[m][n] = (f32x4){0.f, 0.f, 0.f, 0.f};

  auto STAGE = [&](int buf, int k0) {
#pragma unroll
    for (int i = 0; i < 4; i++) {
      int chunk = i * 4 + w;                   // wave-uniform
      int c_lin = chunk * 64 + lane;
      int row = c_lin >> 3;
      int kc = ((c_lin & 7) ^ (row & 7)) * 8;  // inverse-swizzled source k
      int growA = brow + row; growA = growA < M ? growA : M - 1;
      gload16(A + (size_t)growA * lda + k0 + kc, &As[buf][chunk * 512]);
      gload16(Bt + (size_t)(bcol + row) * ldb + k0 + kc, &Bs[buf][chunk * 512]);
    }
  };

  const int nk = K >> 6;
  STAGE(0, 0);
  __syncthreads();
  int buf = 0;
  for (int t = 0; t < nk; t++) {
    if (t + 1 < nk) STAGE(buf ^ 1, (t + 1) << 6);
#pragma unroll
    for (int kk = 0; kk < 2; kk++) {
      const int ke = kk * 32 + (lane >> 4) * 8;
      bf16x8 af[4], bq[4];
#pragma unroll
      for (int m = 0; m < 4; m++) {
        int row = wr * 64 + m * 16 + (lane & 15);
        af[m] = *(const bf16x8*)(&As[buf][row * 64 + (ke ^ ((row & 7) << 3))]);
      }
#pragma unroll
      for (int n = 0; n < 4; n++) {
        int col = wc * 64 + n * 16 + (lane & 15);
        bq[n] = *(const bf16x8*)(&Bs[buf][col * 64 + (ke ^ ((col & 7) << 3))]);
      }
#pragma unroll
      for (int m = 0; m < 4; m++)
#pragma unroll
        for (int n = 0; n < 4; n++)
          acc[m][n] = __builtin_amdgcn_mfma_f32_16x16x32_bf16(af[m], bq[n], acc[m][n], 0, 0, 0);
    }
    __syncthreads();
    buf ^= 1;
  }

#pragma unroll
  for (int m = 0; m < 4; m++) {
    int gr0 = brow + wr * 64 + m * 16 + (lane >> 4) * 4;
#pragma unroll
    for (int n = 0; n < 4; n++) {
      int gc = bcol + wc * 64 + n * 16 + (lane & 15);
      float bv = bias ? bias[gc] : 0.f;
#pragma unroll
      for (int r = 0; r < 4; r++) {
        int gr = gr0 + r;
        if (gr < M) {
          float v = acc[m][n][r] + bv;
          if (act) v = fmaxf(v, 0.f);
          stf(&C[(size_t)gr * ldc + gc], v);
        }
      }
    }
  }
}

// ---------------------------------------------------------------------------
// Weight preparation
// ---------------------------------------------------------------------------
struct FuseArgs {
  const float* W[12];
  const float* rel[12];
  const float* bin[12];
  float* out[12];
  float* bout[12];
};
struct TrArgs {            // 20x [512,512] fp32 -> bf16 transposed (into packs)
  const float* src[20];
  bf16* dst[20];
};
struct CopyB { const float* src[4]; float* dst[4]; };

__global__ __launch_bounds__(256)
void gemm_fuse(FuseArgs fa)
{
  int c = blockIdx.z >> 2, h = blockIdx.z & 3;
  const float* A = fa.W[c] + h * 128;
  const float* B = fa.rel[c] + (size_t)h * 128 * 128;
  float* C = fa.out[c] + h * 128;
  __shared__ float Ast[64][17];
  __shared__ float Bst[16][64];
  const int tid = threadIdx.x;
  const int tx = tid & 15, ty = tid >> 4;
  const int bm = blockIdx.x * 64, bn = blockIdx.y * 64;
  float acc[4][4] = {};
  for (int k0 = 0; k0 < 128; k0 += 16) {
#pragma unroll
    for (int i = 0; i < 4; i++) {
      int lin = tid + i * 256;
      int m = lin >> 4, kk = lin & 15;
      Ast[m][kk] = A[(size_t)(bm + m) * 512 + k0 + kk];
      int kb = lin >> 6, nb = lin & 63;
      Bst[kb][nb] = B[(size_t)(k0 + kb) * 128 + bn + nb];
    }
    __syncthreads();
#pragma unroll
    for (int kk = 0; kk < 16; kk++) {
      float a[4], b[4];
#pragma unroll
      for (int i = 0; i < 4; i++) a[i] = Ast[ty * 4 + i][kk];
#pragma unroll
      for (int j = 0; j < 4; j++) b[j] = Bst[kk][tx * 4 + j];
#pragma unroll
      for (int i = 0; i < 4; i++)
#pragma unroll
        for (int j = 0; j < 4; j++)
          acc[i][j] = fmaf(a[i], b[j], acc[i][j]);
    }
    __syncthreads();
  }
#pragma unroll
  for (int i = 0; i < 4; i++)
#pragma unroll
    for (int j = 0; j < 4; j++)
      C[(size_t)(bm + ty * 4 + i) * 512 + bn + tx * 4 + j] = acc[i][j];
}

__global__ __launch_bounds__(256)
void transpose20(TrArgs ta)
{
  int c = blockIdx.z;
  const float* in = ta.src[c];
  bf16* o = ta.dst[c];
  __shared__ float t[32][33];
  int bn = blockIdx.x * 32, bk = blockIdx.y * 32;
  int x = threadIdx.x, y = threadIdx.y;
#pragma unroll
  for (int i = 0; i < 32; i += 8)
    t[y + i][x] = in[(size_t)(bk + y + i) * 512 + bn + x];
  __syncthreads();
#pragma unroll
  for (int i = 0; i < 32; i += 8)
    o[(size_t)(bn + y + i) * 512 + bk + x] = __float2bfloat16(t[x][y + i]);
}

__global__ __launch_bounds__(512)
void bias_fuse_all(FuseArgs fa)
{
  int c = blockIdx.x;
  int j = threadIdx.x;
  int h = j >> 7, e = j & 127;
  const float* bh = fa.bin[c] + h * DH;
  const float* rh = fa.rel[c] + (size_t)h * DH * DH;
  float s = 0.f;
  for (int d = 0; d < DH; d++) s = fmaf(bh[d], rh[d * DH + e], s);
  fa.bout[c][j] = s;
}

__global__ __launch_bounds__(512)
void copy_bias(CopyB cb)
{
  cb.dst[blockIdx.x][threadIdx.x] = cb.src[blockIdx.x][threadIdx.x];
}

__global__ __launch_bounds__(256)
void transpose_to_bf16(const float* __restrict__ in, bf16* __restrict__ out,
                       int K_, int N_)
{
  __shared__ float t[32][33];
  int bn = blockIdx.x * 32, bk = blockIdx.y * 32;
  int x = threadIdx.x, y = threadIdx.y;
#pragma unroll
  for (int i = 0; i < 32; i += 8) {
    int k = bk + y + i, n = bn + x;
    if (k < K_ && n < N_) t[y + i][x] = in[(size_t)k * N_ + n];
  }
  __syncthreads();
#pragma unroll
  for (int i = 0; i < 32; i += 8) {
    int n = bn + y + i, k = bk + x;
    if (n < N_ && k < K_) out[(size_t)n * K_ + k] = __float2bfloat16(t[x][y + i]);
  }
}

__global__ __launch_bounds__(256)
void f32_to_bf16(const float* __restrict__ x, bf16* __restrict__ y, long long n)
{
  long long i = ((long long)blockIdx.x * 256 + threadIdx.x) * 4;
  if (i >= n) return;
  float4 v = *(const float4*)(x + i);
  ushort4 o;
  o.x = f2bu(v.x); o.y = f2bu(v.y); o.z = f2bu(v.z); o.w = f2bu(v.w);
  *(ushort4*)(y + i) = o;
}

// ---------------------------------------------------------------------------
// CSR build
// ---------------------------------------------------------------------------
__global__ __launch_bounds__(256)
void build_hist(const int* __restrict__ ei_dst, int E, int* __restrict__ deg)
{
  int i = blockIdx.x * 256 + threadIdx.x;
  if (i < E) atomicAdd(&deg[ei_dst[i]], 1);
}

__global__ __launch_bounds__(256)
void scan_blk(const int* __restrict__ deg, int n, int* __restrict__ rowptr,
              int* __restrict__ bsum)
{
  __shared__ int sh[256];
  int t = threadIdx.x;
  int base = blockIdx.x * 1024 + t * 4;
  int v0 = 0, v1 = 0, v2 = 0, v3 = 0;
  if (base + 3 < n) {
    int4 v = *(const int4*)(deg + base);
    v0 = v.x; v1 = v.y; v2 = v.z; v3 = v.w;
  } else {
    if (base < n)     v0 = deg[base];
    if (base + 1 < n) v1 = deg[base + 1];
    if (base + 2 < n) v2 = deg[base + 2];
    if (base + 3 < n) v3 = deg[base + 3];
  }
  int s = v0 + v1 + v2 + v3;
  sh[t] = s;
  __syncthreads();
#pragma unroll
  for (int off = 1; off < 256; off <<= 1) {
    int tv = (t >= off) ? sh[t - off] : 0;
    __syncthreads();
    sh[t] += tv;
    __syncthreads();
  }
  int excl = sh[t] - s;
  if (t == 255) bsum[blockIdx.x] = sh[255];
  if (base < n)     rowptr[base] = excl;
  if (base + 1 < n) rowptr[base + 1] = excl + v0;
  if (base + 2 < n) rowptr[base + 2] = excl + v0 + v1;
  if (base + 3 < n) rowptr[base + 3] = excl + v0 + v1 + v2;
}

__global__ __launch_bounds__(64)
void scan_bsum(int* __restrict__ bsum, int nb, int* __restrict__ rowptr_end)
{
  int t = threadIdx.x;
  int v = (t < nb) ? bsum[t] : 0;
  int inc = v;
#pragma unroll
  for (int off = 1; off < 64; off <<= 1) {
    int o = __shfl_up(inc, off);
    if (t >= off) inc += o;
  }
  if (t < nb) bsum[t] = inc - v;
  if (t == nb - 1) *rowptr_end = inc;
}

__global__ __launch_bounds__(256)
void scan_add(int* __restrict__ rowptr, const int* __restrict__ bsum, int n)
{
  int add = bsum[blockIdx.x];
  if (add == 0) return;
  int i = blockIdx.x * 1024 + threadIdx.x * 4;
  if (i < n)     rowptr[i] += add;
  if (i + 1 < n) rowptr[i + 1] += add;
  if (i + 2 < n) rowptr[i + 2] += add;
  if (i + 3 < n) rowptr[i + 3] += add;
}

__global__ __launch_bounds__(256)
void build_scatter(const int* __restrict__ ei, int E, int flag,
                   const int* __restrict__ rowptr, int* __restrict__ cursor,
                   int* __restrict__ srcs)
{
  int e = blockIdx.x * 256 + threadIdx.x;
  if (e >= E) return;
  int src = ei[e];
  int dst = ei[E + e];
  int pos = rowptr[dst] + atomicAdd(&cursor[dst], 1);
  srcs[pos] = src | flag;
}

// ---------------------------------------------------------------------------
// Fused one-pass attention per destination node (online softmax, defer-max
// THR=8 per T13) + exact gelu -> bf16 row. One 64-lane wave per node.
// Edge tables: t0 (flag 0) / t1 (flag 0x40000000); kr at col off, vr at
// off+512 of the same row. q at col 0 of the q table.
// ---------------------------------------------------------------------------
__global__ __launch_bounds__(256)
void csr_attn_agg(const int* __restrict__ rowptr, const int* __restrict__ srcs,
                  int nnode,
                  const bf16* __restrict__ q, int ldq,
                  const bf16* __restrict__ t0, int ld0, int off0,
                  const bf16* __restrict__ t1, int ld1, int off1,
                  const float* __restrict__ pr0, const float* __restrict__ pr1,
                  float scale, bf16* __restrict__ outb)
{
  int node = blockIdx.x * 4 + (threadIdx.x >> 6);
  if (node >= nnode) return;
  int lane = threadIdx.x & 63;
  int h = lane >> 4;
  float qv[8];
  load8b(q + (size_t)node * ldq, lane, qv);
  float p0 = pr0[h] * scale, p1 = pr1[h] * scale;
  int beg = rowptr[node], end = rowptr[node + 1];
  float m = -INFINITY, s = 0.f;
  float acc[8] = {};
  for (int p = beg; p < end; ++p) {
    int se = srcs[p];
    int src = se & 0x3FFFFFFF;
    bool f1 = (se & 0x40000000) != 0;
    const bf16* row = f1 ? (t1 + (size_t)src * ld1 + off1)
                         : (t0 + (size_t)src * ld0 + off0);
    float kv[8], vv[8];
    load8b(row, lane, kv);
    load8b(row + 512, lane, vv);
    float a = 0.f;
#pragma unroll
    for (int i = 0; i < 8; i++) a = fmaf(qv[i], kv[i], a);
    a += __shfl_xor(a, 1);
    a += __shfl_xor(a, 2);
    a += __shfl_xor(a, 4);
    a += __shfl_xor(a, 8);
    a *= f1 ? p1 : p0;
    if (a > m + 8.f) {            // defer-max: rescale only on big jumps
      float sc = __expf(m - a);   // exp(-inf)=0 on first edge
      s *= sc;
#pragma unroll
      for (int i = 0; i < 8; i++) acc[i] *= sc;
      m = a;
    }
    float wgt = __expf(a - m);    // bounded by e^8
    s += wgt;
#pragma unroll
    for (int i = 0; i < 8; i++) acc[i] = fmaf(wgt, vv[i], acc[i]);
  }
  float inv = 1.f / (s + 1e-16f);
  unsigned short g[8];
#pragma unroll
  for (int i = 0; i < 8; i++) {
    float v = acc[i] * inv;
    g[i] = f2bu(0.5f * v * (1.f + erff(v * 0.70710678118654752f)));
  }
  uint4 o;
  o.x = g[0] | ((unsigned)g[1] << 16);
  o.y = g[2] | ((unsigned)g[3] << 16);
  o.z = g[4] | ((unsigned)g[5] << 16);
  o.w = g[6] | ((unsigned)g[7] << 16);
  *(uint4*)(outb + (size_t)node * HID + lane * 8) = o;
}

// h[row,:] = relu(LN(sp*oplin + (2-sp)*h)) ; oplin fp32, h bf16 in/out
__global__ __launch_bounds__(256)
void skip_ln_relu_bf(const float* __restrict__ oplin, bf16* __restrict__ h,
                     const float* __restrict__ skipv,
                     const float* __restrict__ g, const float* __restrict__ b,
                     int rows)
{
  int row = blockIdx.x;
  if (row >= rows) return;
  float sp = 1.f / (1.f + expf(-skipv[0]));
  const float2* o2 = (const float2*)(oplin + (size_t)row * HID);
  ushort2* h2 = (ushort2*)(h + (size_t)row * HID);
  int t = threadIdx.x;
  float2 ov = o2[t];
  ushort2 hv = h2[t];
  float t0 = sp * ov.x + (2.f - sp) * bu2f(hv.x);
  float t1 = sp * ov.y + (2.f - sp) * bu2f(hv.y);
  float s = t0 + t1, ss = t0 * t0 + t1 * t1;
#pragma unroll
  for (int off = 32; off; off >>= 1) {
    s += __shfl_down(s, off);
    ss += __shfl_down(ss, off);
  }
  __shared__ float sh[8];
  int wid = t >> 6, lane = t & 63;
  if (lane == 0) { sh[wid] = s; sh[4 + wid] = ss; }
  __syncthreads();
  if (t == 0) {
    float S = 0, SS = 0;
    for (int wv = 0; wv < 4; wv++) { S += sh[wv]; SS += sh[4 + wv]; }
    sh[0] = S; sh[4] = SS;
  }
  __syncthreads();
  float mu = sh[0] * (1.f / 512.f);
  float var = sh[4] * (1.f / 512.f) - mu * mu;
  float inv = rsqrtf(var + 1e-5f);
  float y0 = (t0 - mu) * inv * g[2 * t] + b[2 * t];
  float y1 = (t1 - mu) * inv * g[2 * t + 1] + b[2 * t + 1];
  ushort2 o;
  o.x = f2bu(fmaxf(y0, 0.f));
  o.y = f2bu(fmaxf(y1, 0.f));
  h2[t] = o;
}

// ---------------------------------------------------------------------------
template<typename TC>
static inline void mgemm(const bf16* A, int lda, const bf16* Bt, int ldb,
                         const float* bias, TC* C, int ldc,
                         int M, int N, int K, int act, hipStream_t s)
{
  int nbm = (M + 127) / 128, nbn = N / 128;
  dim3 grid(nbm * nbn), block(256);
  mfma_gemm<TC><<<grid, block, 0, s>>>(A, lda, Bt, ldb, bias, C, ldc, M, N, K, act, nbn);
}

extern "C" void kernel_launch(void* const* d_in, const int* in_sizes, int n_in,
                              void* d_out, int out_size, void* d_ws, size_t ws_size,
                              hipStream_t stream)
{
  const float* x_paper  = (const float*)d_in[0];
  const float* x_author = (const float*)d_in[1];
  const float* Wp_paper = (const float*)d_in[2];
  const float* bp_paper = (const float*)d_in[3];
  const float* Wp_author= (const float*)d_in[4];
  const float* bp_author= (const float*)d_in[5];
  const float* Wk = (const float*)d_in[6];
  const float* bk = (const float*)d_in[7];
  const float* Wq = (const float*)d_in[8];
  const float* bq = (const float*)d_in[9];
  const float* Wv = (const float*)d_in[10];
  const float* bv = (const float*)d_in[11];
  const float* Wa = (const float*)d_in[12];
  const float* ba = (const float*)d_in[13];
  const float* skip = (const float*)d_in[14];
  const float* a_rel = (const float*)d_in[15];
  const float* m_rel = (const float*)d_in[16];
  const float* p_rel = (const float*)d_in[17];
  const float* ln_g = (const float*)d_in[18];
  const float* ln_b = (const float*)d_in[19];
  const float* W256 = (const float*)d_in[20];
  const float* b256 = (const float*)d_in[21];
  const float* W128 = (const float*)d_in[22];
  const float* b128 = (const float*)d_in[23];
  const int* ei_c = (const int*)d_in[24];
  const int* ei_w = (const int*)d_in[25];
  const int* ei_b = (const int*)d_in[26];
  float* out = (float*)d_out;

  const size_t NPe = (size_t)NP * HID, NAe = (size_t)NA * HID;
  const size_t HH = (size_t)HID * HID;
  const int NQP = HID + 2 * 1024;   // 2560: q | kv0 | kv2
  const int NQA = HID + 1024;       // 1536: q | kv1
  char* w = (char*)d_ws;
  size_t off = 0;
  auto alloc = [&](size_t bytes) -> void* {
    void* p = (void*)(w + off);
    off += (bytes + 255) & ~(size_t)255;
    return p;
  };
  bf16* hb_p  = (bf16*)alloc(NPe * 2);
  bf16* hb_a  = (bf16*)alloc(NAe * 2);
  bf16* qkv_p = (bf16*)alloc((size_t)NP * NQP * 2);  // xb_p -> q|kv0|kv2 -> oplin f32
  bf16* qkv_a = (bf16*)alloc((size_t)NA * NQA * 2);  // xb_a -> q|kv1 -> oplin f32
  bf16* ag_p  = (bf16*)alloc(NPe * 2);               // gelu(agg) -> h256
  bf16* ag_a  = (bf16*)alloc(NAe * 2);
  float* Wf32 = (float*)alloc(12 * HH * 4);
  bf16* WBtP  = (bf16*)alloc((size_t)2 * NQP * HID * 2);  // per-layer B packs
  bf16* WBtA  = (bf16*)alloc((size_t)2 * NQA * HID * 2);
  float* pbP  = (float*)alloc((size_t)2 * NQP * 4);       // per-layer bias packs
  float* pbA  = (float*)alloc((size_t)2 * NQA * 4);
  bf16* WaT   = (bf16*)alloc(4 * HH * 2);
  bf16* W256T = (bf16*)alloc((size_t)HID * 256 * 2);
  bf16* W128T = (bf16*)alloc((size_t)256 * 128 * 2);
  bf16* WpTp  = (bf16*)alloc((size_t)INDIM * HID * 2);
  bf16* WpTa  = (bf16*)alloc((size_t)INDIM * HID * 2);
  int* rowptrP = (int*)alloc((size_t)(NP + 1) * 4);
  int* degP    = (int*)alloc((size_t)NP * 4);
  int* srcsP   = (int*)alloc((size_t)(EC + EW) * 4);
  int* rowptrA = (int*)alloc((size_t)(NA + 1) * 4);
  int* degA    = (int*)alloc((size_t)NA * 4);
  int* srcsA   = (int*)alloc((size_t)EB * 4);
  int* bsumP   = (int*)alloc(64 * 4);
  int* bsumA   = (int*)alloc(64 * 4);
  if (off > ws_size) return;

  const float scale = 0.08838834764831845f;  // 1/sqrt(128)
  const int nbP = (NP + 1023) / 1024, nbA = (NA + 1023) / 1024;

  // --- CSR build ---
  hipMemsetAsync(degP, 0, (size_t)NP * 4, stream);
  hipMemsetAsync(degA, 0, (size_t)NA * 4, stream);
  build_hist<<<dim3((EC + 255) / 256), 256, 0, stream>>>(ei_c + EC, EC, degP);
  build_hist<<<dim3((EW + 255) / 256), 256, 0, stream>>>(ei_w + EW, EW, degP);
  build_hist<<<dim3((EB + 255) / 256), 256, 0, stream>>>(ei_b + EB, EB, degA);
  scan_blk<<<dim3(nbP), 256, 0, stream>>>(degP, NP, rowptrP, bsumP);
  scan_bsum<<<dim3(1), 64, 0, stream>>>(bsumP, nbP, rowptrP + NP);
  scan_add<<<dim3(nbP), 256, 0, stream>>>(rowptrP, bsumP, NP);
  scan_blk<<<dim3(nbA), 256, 0, stream>>>(degA, NA, rowptrA, bsumA);
  scan_bsum<<<dim3(1), 64, 0, stream>>>(bsumA, nbA, rowptrA + NA);
  scan_add<<<dim3(nbA), 256, 0, stream>>>(rowptrA, bsumA, NA);
  hipMemsetAsync(degP, 0, (size_t)NP * 4, stream);
  hipMemsetAsync(degA, 0, (size_t)NA * 4, stream);
  build_scatter<<<dim3((EC + 255) / 256), 256, 0, stream>>>(ei_c, EC, 0,
      rowptrP, degP, srcsP);
  build_scatter<<<dim3((EW + 255) / 256), 256, 0, stream>>>(ei_w, EW, 0x40000000,
      rowptrP, degP, srcsP);
  build_scatter<<<dim3((EB + 255) / 256), 256, 0, stream>>>(ei_b, EB, 0,
      rowptrA, degA, srcsA);

  // --- fused relation weights + layer packs ---
  FuseArgs fa;
  TrArgs ta;
  CopyB cb;
  for (int l = 0; l < NLAY; l++) {
    bf16* packP = WBtP + (size_t)l * NQP * HID;
    bf16* packA = WBtA + (size_t)l * NQA * HID;
    float* pbPl = pbP + (size_t)l * NQP;
    float* pbAl = pbA + (size_t)l * NQA;
    for (int r = 0; r < 3; r++)
      for (int s = 0; s < 2; s++) {
        int c = (l * 3 + r) * 2 + s;
        int t = (r == 1) ? 1 : 0;
        fa.W[c]   = (s == 0 ? Wk : Wv) + (size_t)(l * 2 + t) * HH;
        fa.rel[c] = (s == 0 ? a_rel : m_rel) + (size_t)(l * 3 + r) * NHEAD * DH * DH;
        fa.bin[c] = (s == 0 ? bk : bv) + (size_t)(l * 2 + t) * HID;
        fa.out[c] = Wf32 + (size_t)c * HH;
        ta.src[c] = fa.out[c];
        if (r == 0) {        // kv0 -> paper pack rows [512,1536)
          ta.dst[c]  = packP + (size_t)(512 + s * 512) * HID;
          fa.bout[c] = pbPl + 512 + s * 512;
        } else if (r == 1) { // kv1 -> author pack rows [512,1536)
          ta.dst[c]  = packA + (size_t)(512 + s * 512) * HID;
          fa.bout[c] = pbAl + 512 + s * 512;
        } else {             // kv2 -> paper pack rows [1536,2560)
          ta.dst[c]  = packP + (size_t)(1536 + s * 512) * HID;
          fa.bout[c] = pbPl + 1536 + s * 512;
        }
      }
    // Q weights into pack row 0; Wa standalone
    ta.src[12 + l * 2 + 0] = Wq + (size_t)(l * 2 + 0) * HH;
    ta.dst[12 + l * 2 + 0] = packP;
    ta.src[12 + l * 2 + 1] = Wq + (size_t)(l * 2 + 1) * HH;
    ta.dst[12 + l * 2 + 1] = packA;
    ta.src[16 + l * 2 + 0] = Wa + (size_t)(l * 2 + 0) * HH;
    ta.dst[16 + l * 2 + 0] = WaT + (size_t)(l * 2 + 0) * HH;
    ta.src[16 + l * 2 + 1] = Wa + (size_t)(l * 2 + 1) * HH;
    ta.dst[16 + l * 2 + 1] = WaT + (size_t)(l * 2 + 1) * HH;
    cb.src[l * 2 + 0] = bq + (size_t)(l * 2 + 0) * HID;
    cb.dst[l * 2 + 0] = pbPl;
    cb.src[l * 2 + 1] = bq + (size_t)(l * 2 + 1) * HID;
    cb.dst[l * 2 + 1] = pbAl;
  }
  gemm_fuse<<<dim3(8, 2, 48), 256, 0, stream>>>(fa);
  transpose20<<<dim3(16, 16, 20), dim3(32, 8), 0, stream>>>(ta);
  bias_fuse_all<<<dim3(12), 512, 0, stream>>>(fa);
  copy_bias<<<dim3(4), 512, 0, stream>>>(cb);
  {
    dim3 b(32, 8);
    transpose_to_bf16<<<dim3(8, 16), b, 0, stream>>>(W256, W256T, HID, 256);
    transpose_to_bf16<<<dim3(4, 8), b, 0, stream>>>(W128, W128T, 256, 128);
    transpose_to_bf16<<<dim3(16, 24), b, 0, stream>>>(Wp_paper, WpTp, INDIM, HID);
    transpose_to_bf16<<<dim3(16, 24), b, 0, stream>>>(Wp_author, WpTa, INDIM, HID);
  }

  // --- input conversion + projection ---
  bf16* xb_p = qkv_p;
  bf16* xb_a = qkv_a;
  long long nxp = (long long)NP * INDIM, nxa = (long long)NA * INDIM;
  f32_to_bf16<<<dim3((int)((nxp / 4 + 255) / 256)), 256, 0, stream>>>(x_paper, xb_p, nxp);
  f32_to_bf16<<<dim3((int)((nxa / 4 + 255) / 256)), 256, 0, stream>>>(x_author, xb_a, nxa);
  mgemm<bf16>(xb_p, INDIM, WpTp, INDIM, bp_paper, hb_p, HID, NP, HID, INDIM, 0, stream);
  mgemm<bf16>(xb_a, INDIM, WpTa, INDIM, bp_author, hb_a, HID, NA, HID, INDIM, 0, stream);

  for (int l = 0; l < NLAY; l++) {
    const float* prl = p_rel + (size_t)l * 3 * NHEAD;
    const bf16* packP = WBtP + (size_t)l * NQP * HID;
    const bf16* packA = WBtA + (size_t)l * NQA * HID;
    const float* pbPl = pbP + (size_t)l * NQP;
    const float* pbAl = pbA + (size_t)l * NQA;

    // fused projections: q|kv0|kv2 (paper), q|kv1 (author)
    mgemm<bf16>(hb_p, HID, packP, HID, pbPl, qkv_p, NQP, NP, NQP, HID, 0, stream);
    mgemm<bf16>(hb_a, HID, packA, HID, pbAl, qkv_a, NQA, NA, NQA, HID, 0, stream);
    // one-pass attention + gelu
    csr_attn_agg<<<dim3((NP + 3) / 4), 256, 0, stream>>>(
        rowptrP, srcsP, NP,
        qkv_p, NQP, qkv_p, NQP, 512, qkv_a, NQA, 512,
        prl + 0, prl + NHEAD, scale, ag_p);
    csr_attn_agg<<<dim3((NA + 3) / 4), 256, 0, stream>>>(
        rowptrA, srcsA, NA,
        qkv_a, NQA, qkv_p, NQP, 1536, qkv_p, NQP, 1536,
        prl + 2 * NHEAD, prl + 2 * NHEAD, scale, ag_a);
    // output linear (fp32) into now-dead qkv slabs
    float* opl_p = (float*)qkv_p;
    float* opl_a = (float*)qkv_a;
    mgemm<float>(ag_p, HID, WaT + (size_t)(l * 2 + 0) * HH, HID,
                 ba + (size_t)(l * 2 + 0) * HID, opl_p, HID, NP, HID, HID, 0, stream);
    mgemm<float>(ag_a, HID, WaT + (size_t)(l * 2 + 1) * HH, HID,
                 ba + (size_t)(l * 2 + 1) * HID, opl_a, HID, NA, HID, HID, 0, stream);
    // skip + residual + LN + relu
    skip_ln_relu_bf<<<dim3(NP), 256, 0, stream>>>(opl_p, hb_p, skip + (l * 2 + 0),
                                                  ln_g + (size_t)l * HID, ln_b + (size_t)l * HID, NP);
    skip_ln_relu_bf<<<dim3(NA), 256, 0, stream>>>(opl_a, hb_a, skip + (l * 2 + 1),
                                                  ln_g + (size_t)l * HID, ln_b + (size_t)l * HID, NA);
  }

  // final MLP
  bf16* h256_p = ag_p;
  bf16* h256_a = ag_a;
  mgemm<bf16>(hb_p, HID, W256T, HID, b256, h256_p, 256, NP, 256, HID, 1, stream);
  mgemm<float>(h256_p, 256, W128T, 256, b128, out, 128, NP, 128, 256, 0, stream);
  mgemm<bf16>(hb_a, HID, W256T, HID, b256, h256_a, 256, NA, 256, HID, 1, stream);
  mgemm<float>(h256_a, 256, W128T, 256, b128, out + (size_t)NP * 128, 128, NA, 128, 256, 0, stream);
}